// Round 2
// baseline (1294.699 us; speedup 1.0000x reference)
//
#include <hip/hip_runtime.h>
#include <stdint.h>

typedef __bf16 bf16x8 __attribute__((ext_vector_type(8)));
typedef float  f32x4  __attribute__((ext_vector_type(4)));
typedef float  f32x16 __attribute__((ext_vector_type(16)));
typedef unsigned short u16;

// ---- workspace layout (bytes) ----
#define WCT_OFF   0u          // 144*256 bf16 = 73728   (W^T, fused Wq|Wk|Wv)
#define SC_OFF    73728u      // 144 f32 BN scale
#define SH_OFF    74304u      // 144 f32 BN shift
#define BST_OFF   75008u      // 23 * 12288 bf16 = 565248 (banded conv B, frag-lane order)
#define MSUM_OFF  640256u     // 16*16*2 f32 (softmax max, 1/sum)
#define LCB_OFF   642304u     // 16*16*64 f32 (Lc + pos_b)
#define QP_OFF    707840u     // 16*4096*64 bf16 (q, BN'd, [b][pos][ch])
#define KT_OFF    9096448u    // 16*16*4096 bf16 (k, [b][ch][pos])
#define VT_OFF    11193600u   // 16*64*4096 bf16 (v, BN'd, [b][ch][pos] = per-v image)
#define LP_OFF    19582208u   // Lp bf16 [bchunk][pos][v*16+k], 8388608 B per b
#define LP_PER_B  8388608u

// ------------------------------------------------------------------
// Kernel P: precompute WcT (bf16), BN affine, banded conv B matrices
// ------------------------------------------------------------------
__global__ void kP(const float* Wq, const float* Wk, const float* Wv,
                   const float* gq, const float* bq, const float* mq, const float* vq,
                   const float* gv, const float* bv, const float* mv, const float* vvar,
                   const float* pw, char* ws) {
  int t = threadIdx.x;
  if (blockIdx.x == 0) {
    __bf16* wct = (__bf16*)(ws + WCT_OFF);
    for (int i = 0; i < 144; ++i) {
      int n = i, c = t;
      float val;
      if (n < 64)      val = Wq[c * 64 + n];
      else if (n < 80) val = Wk[c * 16 + (n - 64)];
      else             val = Wv[c * 64 + (n - 80)];
      wct[n * 256 + c] = (__bf16)val;
    }
    if (t < 144) {
      float s, sh;
      if (t < 64)      { s = gq[t] * rsqrtf(vq[t] + 1e-3f); sh = bq[t] - mq[t] * s; }
      else if (t < 80) { s = 1.f; sh = 0.f; }
      else { int i = t - 80; s = gv[i] * rsqrtf(vvar[i] + 1e-3f); sh = bv[i] - mv[i] * s; }
      ((float*)(ws + SC_OFF))[t] = s;
      ((float*)(ws + SH_OFF))[t] = sh;
    }
  } else {
    int dy = blockIdx.x - 1;               // 0..22
    __bf16* bst = (__bf16*)(ws + BST_OFF) + dy * 12288;
    for (int i = 0; i < 48; ++i) {
      int idx = i * 256 + t;               // < 12288
      int nt = idx / 1536, r1 = idx % 1536;
      int ks = r1 / 512,   r2 = r1 % 512;
      int l = r2 >> 3, e = r2 & 7;
      int j = ks * 16 + (l >> 5) * 8 + e;  // K index 0..47
      int n = nt * 32 + (l & 31);          // N index 0..255
      int xr = n >> 4, kch = n & 15;
      int dxw = j - xr - 5;                // img col = x + dxw - 11
      float val = (dxw >= 0 && dxw < 23) ? pw[(dy * 23 + dxw) * 16 + kch] : 0.f;
      bst[idx] = (__bf16)val;
    }
  }
}

// ------------------------------------------------------------------
// Kernel A: fused q/k/v projections (M=65536,K=256,N=144) + BN, MFMA 16x16x32
// ------------------------------------------------------------------
__global__ __launch_bounds__(256) void kA(const float* x, char* ws) {
  int t = threadIdx.x, w = t >> 6, l = t & 63;
  int m0 = blockIdx.x * 256;
  int b = m0 >> 12;
  int posb = m0 & 4095;
  const __bf16* wct = (const __bf16*)(ws + WCT_OFF);
  const float* sc = (const float*)(ws + SC_OFF);
  const float* sh = (const float*)(ws + SH_OFF);
  __bf16* qp = (__bf16*)(ws + QP_OFF);
  __bf16* kt = (__bf16*)(ws + KT_OFF);
  __bf16* vt = (__bf16*)(ws + VT_OFF);

  int rl = l & 15;      // A row / B col / C col within frag
  int kg = l >> 4;      // k-group 0..3

  f32x4 acc[4][9];
#pragma unroll
  for (int mf = 0; mf < 4; ++mf)
#pragma unroll
    for (int nf = 0; nf < 9; ++nf)
#pragma unroll
      for (int q = 0; q < 4; ++q) acc[mf][nf][q] = 0.f;

  for (int ks = 0; ks < 8; ++ks) {
    bf16x8 a[4];
#pragma unroll
    for (int mf = 0; mf < 4; ++mf) {
      int m = m0 + w * 64 + mf * 16 + rl;
      const float* xp = x + m * 256 + ks * 32 + kg * 8;
      f32x4 v0 = *(const f32x4*)xp;
      f32x4 v1 = *(const f32x4*)(xp + 4);
      bf16x8 av;
      av[0] = (__bf16)v0[0]; av[1] = (__bf16)v0[1]; av[2] = (__bf16)v0[2]; av[3] = (__bf16)v0[3];
      av[4] = (__bf16)v1[0]; av[5] = (__bf16)v1[1]; av[6] = (__bf16)v1[2]; av[7] = (__bf16)v1[3];
      a[mf] = av;
    }
#pragma unroll
    for (int nf = 0; nf < 9; ++nf) {
      bf16x8 bfr = *(const bf16x8*)(wct + (nf * 16 + rl) * 256 + ks * 32 + kg * 8);
#pragma unroll
      for (int mf = 0; mf < 4; ++mf)
        acc[mf][nf] = __builtin_amdgcn_mfma_f32_16x16x32_bf16(a[mf], bfr, acc[mf][nf], 0, 0, 0);
    }
  }

#pragma unroll
  for (int nf = 0; nf < 9; ++nf) {
    int ch = nf * 16 + rl;
    float s = sc[ch], shv = sh[ch];
#pragma unroll
    for (int mf = 0; mf < 4; ++mf) {
      int pbase = posb + w * 64 + mf * 16 + kg * 4;
      union { __bf16 h[4]; uint2 u; } pk;
#pragma unroll
      for (int r = 0; r < 4; ++r) pk.h[r] = (__bf16)(acc[mf][nf][r] * s + shv);
      if (ch < 64) {
#pragma unroll
        for (int r = 0; r < 4; ++r)
          qp[(size_t)(b * 4096 + pbase + r) * 64 + ch] = pk.h[r];
      } else if (ch < 80) {
        *(uint2*)(kt + (size_t)(b * 16 + ch - 64) * 4096 + pbase) = pk.u;
      } else {
        *(uint2*)(vt + (size_t)(b * 64 + ch - 80) * 4096 + pbase) = pk.u;
      }
    }
  }
}

// ------------------------------------------------------------------
// Kernel B1: per (b, k-channel) softmax max & 1/sum over 4096 positions
// ------------------------------------------------------------------
__global__ void kB1(char* ws) {
  __shared__ float red[256];
  int t = threadIdx.x;
  int b = blockIdx.x >> 4, kk = blockIdx.x & 15;
  const __bf16* kt = (const __bf16*)(ws + KT_OFF) + (size_t)(b * 16 + kk) * 4096;
  float v[16];
  bf16x8 c0 = *(const bf16x8*)(kt + t * 16);
  bf16x8 c1 = *(const bf16x8*)(kt + t * 16 + 8);
#pragma unroll
  for (int i = 0; i < 8; ++i) { v[i] = (float)c0[i]; v[8 + i] = (float)c1[i]; }
  float mx = v[0];
#pragma unroll
  for (int i = 1; i < 16; ++i) mx = fmaxf(mx, v[i]);
  red[t] = mx; __syncthreads();
  for (int s = 128; s > 0; s >>= 1) { if (t < s) red[t] = fmaxf(red[t], red[t + s]); __syncthreads(); }
  mx = red[0]; __syncthreads();
  float se = 0.f;
#pragma unroll
  for (int i = 0; i < 16; ++i) se += expf(v[i] - mx);
  red[t] = se; __syncthreads();
  for (int s = 128; s > 0; s >>= 1) { if (t < s) red[t] += red[t + s]; __syncthreads(); }
  if (t == 0) {
    float* ms = (float*)(ws + MSUM_OFF);
    ms[(b * 16 + kk) * 2] = mx;
    ms[(b * 16 + kk) * 2 + 1] = 1.f / red[0];
  }
}

// ------------------------------------------------------------------
// Kernel B2: LcB[b][k][v] = sum_n softmax(k)[n]*v[v][n] + pos_b[k]
// ------------------------------------------------------------------
__global__ __launch_bounds__(256) void kB2(char* ws, const float* pos_b) {
  __shared__ float red[16][256];
  int t = threadIdx.x;
  int b = blockIdx.x >> 6, v = blockIdx.x & 63;
  const __bf16* kt = (const __bf16*)(ws + KT_OFF) + (size_t)b * 16 * 4096;
  const __bf16* vt = (const __bf16*)(ws + VT_OFF) + (size_t)(b * 64 + v) * 4096;
  const float* ms = (const float*)(ws + MSUM_OFF) + b * 32;
  float mx[16];
#pragma unroll
  for (int i = 0; i < 16; ++i) mx[i] = ms[2 * i];
  float acc[16];
#pragma unroll
  for (int i = 0; i < 16; ++i) acc[i] = 0.f;
  for (int c = 0; c < 16; ++c) {
    int p = c * 256 + t;
    float vv = (float)vt[p];
#pragma unroll
    for (int i = 0; i < 16; ++i)
      acc[i] += expf((float)kt[i * 4096 + p] - mx[i]) * vv;
  }
#pragma unroll
  for (int i = 0; i < 16; ++i) red[i][t] = acc[i];
  __syncthreads();
  for (int s = 128; s > 0; s >>= 1) {
    if (t < s) {
#pragma unroll
      for (int i = 0; i < 16; ++i) red[i][t] += red[i][t + s];
    }
    __syncthreads();
  }
  if (t < 16) {
    float* lcb = (float*)(ws + LCB_OFF);
    lcb[(b * 16 + t) * 64 + v] = red[t][0] * ms[2 * t + 1] + pos_b[t];
  }
}

// ------------------------------------------------------------------
// Kernel C: 23x23 conv as banded GEMM, MFMA 32x32x16 bf16.
// Block = (b, v-pair). M=128 (2v x 64y), N=256 (16x x 16k) per x-tile, K=48/dy.
// B fragments read DIRECTLY from global (L2-resident, frag-lane order) -> the
// main loop has NO barriers; image staged in LDS once up front.
// ------------------------------------------------------------------
__global__ __launch_bounds__(256, 2) void kC(char* ws, int b0) {
  __shared__ __align__(16) u16 imgp[2 * 86 * 128];  // padded images, XOR-swizzled (44032 B)
  int t = threadIdx.x, w = t >> 6, l = t & 63;
  int bb = blockIdx.x >> 5;
  int b = b0 + bb;
  int vp = blockIdx.x & 31;
  int vbase = vp * 2;
  const __bf16* vt = (const __bf16*)(ws + VT_OFF);
  const u16* bst = (const u16*)(ws + BST_OFF);
  __bf16* lp = (__bf16*)(ws + LP_OFF) + (size_t)bb * 4194304;

  // zero the padded image buffer
  bf16x8 z;
#pragma unroll
  for (int q = 0; q < 8; ++q) z[q] = (__bf16)0.f;
#pragma unroll
  for (int i = 0; i < 11; ++i) {
    int idx = (t + i * 256) * 8;
    if (idx < 22016) *(bf16x8*)(imgp + idx) = z;
  }
  __syncthreads();
  // stage interior (zero halo: rows 11..74, logical cols 16..79), swizzled
#pragma unroll
  for (int i = 0; i < 4; ++i) {
    int slot = t + i * 256;            // < 1024 = 2v * 64y * 8chunks
    int vs = slot >> 9, s2 = slot & 511;
    int y = s2 >> 3, xc = (s2 & 7) * 8;
    bf16x8 val = *(const bf16x8*)(vt + (size_t)(b * 64 + vbase + vs) * 4096 + y * 64 + xc);
    int r = 11 + y;
    int col = (16 + xc) ^ ((r & 15) << 3);
    *(bf16x8*)(imgp + vs * 11008 + r * 128 + col) = val;
  }
  __syncthreads();

  int wm = (w >> 1) * 64, wn = (w & 1) * 128;
  // per-lane B-fragment base offsets (u16 elements) within one dy block
  int boff[4][3];
#pragma unroll
  for (int nf = 0; nf < 4; ++nf) {
    int nt = (wn >> 5) + nf;
#pragma unroll
    for (int ks = 0; ks < 3; ++ks)
      boff[nf][ks] = ((nt * 3 + ks) * 64 + l) * 8;
  }

  for (int xt = 0; xt < 4; ++xt) {
    int x0 = xt * 16;
    f32x16 acc[2][4];
#pragma unroll
    for (int mf = 0; mf < 2; ++mf)
#pragma unroll
      for (int nf = 0; nf < 4; ++nf)
#pragma unroll
        for (int q = 0; q < 16; ++q) acc[mf][nf][q] = 0.f;

#pragma unroll
    for (int dy = 0; dy < 23; ++dy) {
      const u16* bdy = bst + dy * 12288;
      // A fragments from LDS (no barrier needed; image is read-only now)
      bf16x8 a[2][3];
#pragma unroll
      for (int mf = 0; mf < 2; ++mf) {
        int row = wm + mf * 32 + (l & 31);
        int vs = row >> 6, y = row & 63;
        int r = y + dy;
        const u16* base = imgp + vs * 11008 + r * 128;
#pragma unroll
        for (int ks = 0; ks < 3; ++ks) {
          int col = (x0 + ks * 16 + (l >> 5) * 8) ^ ((r & 15) << 3);
          a[mf][ks] = *(const bf16x8*)(base + col);
        }
      }
      // B fragments straight from global (L2-resident)
      bf16x8 bf_[4][3];
#pragma unroll
      for (int nf = 0; nf < 4; ++nf)
#pragma unroll
        for (int ks = 0; ks < 3; ++ks)
          bf_[nf][ks] = *(const bf16x8*)(bdy + boff[nf][ks]);
#pragma unroll
      for (int nf = 0; nf < 4; ++nf) {
#pragma unroll
        for (int ks = 0; ks < 3; ++ks) {
          acc[0][nf] = __builtin_amdgcn_mfma_f32_32x32x16_bf16(a[0][ks], bf_[nf][ks], acc[0][nf], 0, 0, 0);
          acc[1][nf] = __builtin_amdgcn_mfma_f32_32x32x16_bf16(a[1][ks], bf_[nf][ks], acc[1][nf], 0, 0, 0);
        }
      }
    }
    // epilogue: Lp[pos][v*16+k] bf16
#pragma unroll
    for (int mf = 0; mf < 2; ++mf) {
#pragma unroll
      for (int nf = 0; nf < 4; ++nf) {
        int n = wn + nf * 32 + (l & 31);
        int x = x0 + (n >> 4), kch = n & 15;
#pragma unroll
        for (int r = 0; r < 16; ++r) {
          int row = wm + mf * 32 + (r & 3) + 8 * (r >> 2) + 4 * (l >> 5);
          int v = vbase + (row >> 6), y = row & 63;
          lp[(size_t)(y * 64 + x) * 1024 + v * 16 + kch] = (__bf16)acc[mf][nf][r];
        }
      }
    }
  }
}

// ------------------------------------------------------------------
// Kernel D: Y[b][pos][h*64+v] = sum_k q[pos][h*16+k]*(LcB[k][v] + Lp[pos][v*16+k])
// ------------------------------------------------------------------
__global__ __launch_bounds__(256) void kD(const char* ws, float* out, int b0) {
  int t = threadIdx.x;
  int h = t >> 6, v = t & 63;
  int bb = blockIdx.x >> 6, pt = blockIdx.x & 63;
  int b = b0 + bb;
  const __bf16* qp = (const __bf16*)(ws + QP_OFF) + (size_t)b * 4096 * 64;
  const __bf16* lp = (const __bf16*)(ws + LP_OFF) + (size_t)bb * 4194304;
  const float* lcb = (const float*)(ws + LCB_OFF) + b * 1024;
  float lc[16];
#pragma unroll
  for (int i = 0; i < 16; ++i) lc[i] = lcb[i * 64 + v];
  int p0 = pt * 64;
  for (int pp = 0; pp < 64; ++pp) {
    int p = p0 + pp;
    const __bf16* qrow = qp + (size_t)p * 64 + h * 16;
    const __bf16* lrow = lp + (size_t)p * 1024 + v * 16;
    bf16x8 q0 = *(const bf16x8*)qrow;
    bf16x8 q1 = *(const bf16x8*)(qrow + 8);
    bf16x8 l0 = *(const bf16x8*)lrow;
    bf16x8 l1 = *(const bf16x8*)(lrow + 8);
    float sum = 0.f;
#pragma unroll
    for (int i = 0; i < 8; ++i) {
      sum += (float)q0[i] * (lc[i] + (float)l0[i]);
      sum += (float)q1[i] * (lc[8 + i] + (float)l1[i]);
    }
    out[((size_t)b * 4096 + p) * 256 + t] = sum;
  }
}

extern "C" void kernel_launch(void* const* d_in, const int* in_sizes, int n_in,
                              void* d_out, int out_size, void* d_ws, size_t ws_size,
                              hipStream_t stream) {
  const float* x   = (const float*)d_in[0];
  const float* Wq  = (const float*)d_in[1];
  const float* Wk  = (const float*)d_in[2];
  const float* Wv  = (const float*)d_in[3];
  const float* gq  = (const float*)d_in[4];
  const float* bq  = (const float*)d_in[5];
  const float* mq  = (const float*)d_in[6];
  const float* vq  = (const float*)d_in[7];
  const float* gv  = (const float*)d_in[8];
  const float* bv  = (const float*)d_in[9];
  const float* mv  = (const float*)d_in[10];
  const float* vvr = (const float*)d_in[11];
  const float* pw  = (const float*)d_in[12];
  const float* pb  = (const float*)d_in[13];
  char* ws = (char*)d_ws;
  float* out = (float*)d_out;

  hipLaunchKernelGGL(kP, dim3(24), dim3(256), 0, stream,
                     Wq, Wk, Wv, gq, bq, mq, vq, gv, bv, mv, vvr, pw, ws);
  hipLaunchKernelGGL(kA, dim3(256), dim3(256), 0, stream, x, ws);
  hipLaunchKernelGGL(kB1, dim3(256), dim3(256), 0, stream, ws);
  hipLaunchKernelGGL(kB2, dim3(1024), dim3(256), 0, stream, ws, pb);

  size_t avail = ws_size > LP_OFF ? ws_size - LP_OFF : 0;
  int nb = (int)(avail / LP_PER_B);
  if (nb < 1) nb = 1;
  if (nb > 16) nb = 16;
  for (int b0 = 0; b0 < 16; b0 += nb) {
    int cur = (16 - b0 < nb) ? 16 - b0 : nb;
    hipLaunchKernelGGL(kC, dim3(cur * 32), dim3(256), 0, stream, ws, b0);
    hipLaunchKernelGGL(kD, dim3(cur * 64), dim3(256), 0, stream, ws, out, b0);
  }
}

// Round 3
// 275.153 us; speedup vs baseline: 4.7054x; 4.7054x over previous
//
#include <hip/hip_runtime.h>
#include <stdint.h>

typedef __bf16 bf16x8 __attribute__((ext_vector_type(8)));
typedef float  f32x4  __attribute__((ext_vector_type(4)));
typedef float  f32x16 __attribute__((ext_vector_type(16)));
typedef unsigned short u16;

// ---- workspace layout (bytes) ----
#define WCT_OFF   0u          // 144*256 bf16 = 73728   (W^T, fused Wq|Wk|Wv)
#define SC_OFF    73728u      // 144 f32 BN scale
#define SH_OFF    74304u      // 144 f32 BN shift
#define BST_OFF   75008u      // 23 * 12288 bf16 = 565248 (banded conv B, frag-lane order)
#define MSUM_OFF  640256u     // 16*16*2 f32 (softmax max, 1/sum)
#define LCB_OFF   642304u     // 16*16*64 f32 (Lc + pos_b)
#define QP_OFF    707840u     // 16*4096*64 bf16 (q, BN'd, [b][pos][ch])
#define KT_OFF    9096448u    // 16*16*4096 bf16 (k, [b][ch][pos])
#define VT_OFF    11193600u   // 16*64*4096 bf16 (v, BN'd, [b][ch][pos] = per-v image)
#define LP_OFF    19582208u   // Lp bf16 [bchunk][pos][v*16+k], 8388608 B per b
#define LP_PER_B  8388608u

// ------------------------------------------------------------------
// Kernel P: precompute WcT (bf16), BN affine, banded conv B matrices
// ------------------------------------------------------------------
__global__ void kP(const float* Wq, const float* Wk, const float* Wv,
                   const float* gq, const float* bq, const float* mq, const float* vq,
                   const float* gv, const float* bv, const float* mv, const float* vvar,
                   const float* pw, char* ws) {
  int t = threadIdx.x;
  if (blockIdx.x == 0) {
    __bf16* wct = (__bf16*)(ws + WCT_OFF);
    for (int i = 0; i < 144; ++i) {
      int n = i, c = t;
      float val;
      if (n < 64)      val = Wq[c * 64 + n];
      else if (n < 80) val = Wk[c * 16 + (n - 64)];
      else             val = Wv[c * 64 + (n - 80)];
      wct[n * 256 + c] = (__bf16)val;
    }
    if (t < 144) {
      float s, sh;
      if (t < 64)      { s = gq[t] * rsqrtf(vq[t] + 1e-3f); sh = bq[t] - mq[t] * s; }
      else if (t < 80) { s = 1.f; sh = 0.f; }
      else { int i = t - 80; s = gv[i] * rsqrtf(vvar[i] + 1e-3f); sh = bv[i] - mv[i] * s; }
      ((float*)(ws + SC_OFF))[t] = s;
      ((float*)(ws + SH_OFF))[t] = sh;
    }
  } else {
    int dy = blockIdx.x - 1;               // 0..22
    __bf16* bst = (__bf16*)(ws + BST_OFF) + dy * 12288;
    for (int i = 0; i < 48; ++i) {
      int idx = i * 256 + t;               // < 12288
      int nt = idx / 1536, r1 = idx % 1536;
      int ks = r1 / 512,   r2 = r1 % 512;
      int l = r2 >> 3, e = r2 & 7;
      int j = ks * 16 + (l >> 5) * 8 + e;  // K index 0..47
      int n = nt * 32 + (l & 31);          // N index 0..255
      int xr = n >> 4, kch = n & 15;
      int dxw = j - xr - 5;                // img col = x + dxw - 11
      float val = (dxw >= 0 && dxw < 23) ? pw[(dy * 23 + dxw) * 16 + kch] : 0.f;
      bst[idx] = (__bf16)val;
    }
  }
}

// ------------------------------------------------------------------
// Kernel A: fused q/k/v projections (M=65536,K=256,N=144) + BN, MFMA 16x16x32
// ------------------------------------------------------------------
__global__ __launch_bounds__(256) void kA(const float* x, char* ws) {
  int t = threadIdx.x, w = t >> 6, l = t & 63;
  int m0 = blockIdx.x * 256;
  int b = m0 >> 12;
  int posb = m0 & 4095;
  const __bf16* wct = (const __bf16*)(ws + WCT_OFF);
  const float* sc = (const float*)(ws + SC_OFF);
  const float* sh = (const float*)(ws + SH_OFF);
  __bf16* qp = (__bf16*)(ws + QP_OFF);
  __bf16* kt = (__bf16*)(ws + KT_OFF);
  __bf16* vt = (__bf16*)(ws + VT_OFF);

  int rl = l & 15;      // A row / B col / C col within frag
  int kg = l >> 4;      // k-group 0..3

  f32x4 acc[4][9];
#pragma unroll
  for (int mf = 0; mf < 4; ++mf)
#pragma unroll
    for (int nf = 0; nf < 9; ++nf)
#pragma unroll
      for (int q = 0; q < 4; ++q) acc[mf][nf][q] = 0.f;

  for (int ks = 0; ks < 8; ++ks) {
    bf16x8 a[4];
#pragma unroll
    for (int mf = 0; mf < 4; ++mf) {
      int m = m0 + w * 64 + mf * 16 + rl;
      const float* xp = x + m * 256 + ks * 32 + kg * 8;
      f32x4 v0 = *(const f32x4*)xp;
      f32x4 v1 = *(const f32x4*)(xp + 4);
      bf16x8 av;
      av[0] = (__bf16)v0[0]; av[1] = (__bf16)v0[1]; av[2] = (__bf16)v0[2]; av[3] = (__bf16)v0[3];
      av[4] = (__bf16)v1[0]; av[5] = (__bf16)v1[1]; av[6] = (__bf16)v1[2]; av[7] = (__bf16)v1[3];
      a[mf] = av;
    }
#pragma unroll
    for (int nf = 0; nf < 9; ++nf) {
      bf16x8 bfr = *(const bf16x8*)(wct + (nf * 16 + rl) * 256 + ks * 32 + kg * 8);
#pragma unroll
      for (int mf = 0; mf < 4; ++mf)
        acc[mf][nf] = __builtin_amdgcn_mfma_f32_16x16x32_bf16(a[mf], bfr, acc[mf][nf], 0, 0, 0);
    }
  }

#pragma unroll
  for (int nf = 0; nf < 9; ++nf) {
    int ch = nf * 16 + rl;
    float s = sc[ch], shv = sh[ch];
#pragma unroll
    for (int mf = 0; mf < 4; ++mf) {
      int pbase = posb + w * 64 + mf * 16 + kg * 4;
      union { __bf16 h[4]; uint2 u; } pk;
#pragma unroll
      for (int r = 0; r < 4; ++r) pk.h[r] = (__bf16)(acc[mf][nf][r] * s + shv);
      if (ch < 64) {
#pragma unroll
        for (int r = 0; r < 4; ++r)
          qp[(size_t)(b * 4096 + pbase + r) * 64 + ch] = pk.h[r];
      } else if (ch < 80) {
        *(uint2*)(kt + (size_t)(b * 16 + ch - 64) * 4096 + pbase) = pk.u;
      } else {
        *(uint2*)(vt + (size_t)(b * 64 + ch - 80) * 4096 + pbase) = pk.u;
      }
    }
  }
}

// ------------------------------------------------------------------
// Kernel B1: per (b, k-channel) softmax max & 1/sum over 4096 positions
// ------------------------------------------------------------------
__global__ void kB1(char* ws) {
  __shared__ float red[256];
  int t = threadIdx.x;
  int b = blockIdx.x >> 4, kk = blockIdx.x & 15;
  const __bf16* kt = (const __bf16*)(ws + KT_OFF) + (size_t)(b * 16 + kk) * 4096;
  float v[16];
  bf16x8 c0 = *(const bf16x8*)(kt + t * 16);
  bf16x8 c1 = *(const bf16x8*)(kt + t * 16 + 8);
#pragma unroll
  for (int i = 0; i < 8; ++i) { v[i] = (float)c0[i]; v[8 + i] = (float)c1[i]; }
  float mx = v[0];
#pragma unroll
  for (int i = 1; i < 16; ++i) mx = fmaxf(mx, v[i]);
  red[t] = mx; __syncthreads();
  for (int s = 128; s > 0; s >>= 1) { if (t < s) red[t] = fmaxf(red[t], red[t + s]); __syncthreads(); }
  mx = red[0]; __syncthreads();
  float se = 0.f;
#pragma unroll
  for (int i = 0; i < 16; ++i) se += expf(v[i] - mx);
  red[t] = se; __syncthreads();
  for (int s = 128; s > 0; s >>= 1) { if (t < s) red[t] += red[t + s]; __syncthreads(); }
  if (t == 0) {
    float* ms = (float*)(ws + MSUM_OFF);
    ms[(b * 16 + kk) * 2] = mx;
    ms[(b * 16 + kk) * 2 + 1] = 1.f / red[0];
  }
}

// ------------------------------------------------------------------
// Kernel B2: LcB[b][k][v] = sum_n softmax(k)[n]*v[v][n] + pos_b[k]
// ------------------------------------------------------------------
__global__ __launch_bounds__(256) void kB2(char* ws, const float* pos_b) {
  __shared__ float red[16][256];
  int t = threadIdx.x;
  int b = blockIdx.x >> 6, v = blockIdx.x & 63;
  const __bf16* kt = (const __bf16*)(ws + KT_OFF) + (size_t)b * 16 * 4096;
  const __bf16* vt = (const __bf16*)(ws + VT_OFF) + (size_t)(b * 64 + v) * 4096;
  const float* ms = (const float*)(ws + MSUM_OFF) + b * 32;
  float mx[16];
#pragma unroll
  for (int i = 0; i < 16; ++i) mx[i] = ms[2 * i];
  float acc[16];
#pragma unroll
  for (int i = 0; i < 16; ++i) acc[i] = 0.f;
  for (int c = 0; c < 16; ++c) {
    int p = c * 256 + t;
    float vv = (float)vt[p];
#pragma unroll
    for (int i = 0; i < 16; ++i)
      acc[i] += expf((float)kt[i * 4096 + p] - mx[i]) * vv;
  }
#pragma unroll
  for (int i = 0; i < 16; ++i) red[i][t] = acc[i];
  __syncthreads();
  for (int s = 128; s > 0; s >>= 1) {
    if (t < s) {
#pragma unroll
      for (int i = 0; i < 16; ++i) red[i][t] += red[i][t + s];
    }
    __syncthreads();
  }
  if (t < 16) {
    float* lcb = (float*)(ws + LCB_OFF);
    lcb[(b * 16 + t) * 64 + v] = red[t][0] * ms[2 * t + 1] + pos_b[t];
  }
}

// ------------------------------------------------------------------
// Kernel C: 23x23 conv as banded GEMM, MFMA 32x32x16 bf16.
// Grid = (b, v-group of 4, x-tile of 16). M=256 (4v x 64y), N=256 (16x x 16k).
// dy loop: B staged to double-buffered LDS via global_load_lds (width 16),
// counted vmcnt(3) + raw s_barrier (prefetch stays in flight across barriers).
// ------------------------------------------------------------------
__global__ __launch_bounds__(512, 2) void kC(char* ws, int b0) {
  __shared__ __align__(16) u16 imgp[4 * 86 * 64];   // [vs][rr][64], swizzled, 44032B
  __shared__ __align__(16) u16 bbuf[2][12288];      // double-buffered B, 24576B each
  int t = threadIdx.x, w = t >> 6, l = t & 63;
  int bb = blockIdx.x >> 6;
  int b = b0 + bb;
  int rest = blockIdx.x & 63;
  int vg = rest >> 2, xt = rest & 3;
  int vbase = vg * 4, x0g = xt * 16;
  const __bf16* vt = (const __bf16*)(ws + VT_OFF);
  const char* bstc = (const char*)(ws + BST_OFF);
  __bf16* lp = (__bf16*)(ws + LP_OFF) + (size_t)bb * 4194304;

  // zero the padded image buffer (2752 x 16B)
  bf16x8 z;
#pragma unroll
  for (int q = 0; q < 8; ++q) z[q] = (__bf16)0.f;
#pragma unroll
  for (int i = 0; i < 6; ++i) {
    int idx = t + i * 512;
    if (idx < 2752) ((bf16x8*)imgp)[idx] = z;
  }
  __syncthreads();
  // stage interior: 4 vs x 64 rows x 6 chunks = 1536 = 3*512
#pragma unroll
  for (int i = 0; i < 3; ++i) {
    int slot = t + i * 512;
    int vs = slot / 384, rem = slot % 384;
    int y = rem / 6, c0 = (rem % 6) * 8;
    int gx = x0g - 16 + c0;
    if (gx >= 0 && gx < 64) {
      bf16x8 val = *(const bf16x8*)(vt + (size_t)(b * 64 + vbase + vs) * 4096 + y * 64 + gx);
      int rr = 11 + y;
      *(bf16x8*)(imgp + vs * 5504 + rr * 64 + (c0 ^ ((rr & 7) << 3))) = val;
    }
  }
  __syncthreads();

  int wm = (w >> 1) * 64, wn = (w & 1) * 128;
  int vsw = w >> 1;                     // this wave's v index within group
  // B fragment offsets (u16) within a bbuf
  int boff[4][3];
#pragma unroll
  for (int nf = 0; nf < 4; ++nf) {
    int nt = (wn >> 5) + nf;
#pragma unroll
    for (int ks = 0; ks < 3; ++ks)
      boff[nf][ks] = ((nt * 3 + ks) * 64 + l) * 8;
  }

  f32x16 acc[2][4];
#pragma unroll
  for (int mf = 0; mf < 2; ++mf)
#pragma unroll
    for (int nf = 0; nf < 4; ++nf)
#pragma unroll
      for (int q = 0; q < 16; ++q) acc[mf][nf][q] = 0.f;

  // async stage helper: 3 x 16B per thread, linear frag-order
#define STAGE_B(bufsel, dyv) do {                                              \
    const char* gsrc = bstc + (dyv) * 24576;                                   \
    char* ldsb = (char*)&bbuf[(bufsel)][0] + w * 1024;                         \
    _Pragma("unroll")                                                          \
    for (int i_ = 0; i_ < 3; ++i_)                                             \
      __builtin_amdgcn_global_load_lds(                                        \
        (const __attribute__((address_space(1))) void*)(gsrc + i_ * 8192 + (w * 64 + l) * 16), \
        (__attribute__((address_space(3))) void*)(ldsb + i_ * 8192), 16, 0, 0);\
  } while (0)

  STAGE_B(0, 0);

  for (int dy = 0; dy < 23; ++dy) {
    int cur = dy & 1;
    if (dy < 22) {
      STAGE_B(cur ^ 1, dy + 1);
      asm volatile("s_waitcnt vmcnt(3)" ::: "memory");
    } else {
      asm volatile("s_waitcnt vmcnt(0)" ::: "memory");
    }
    __builtin_amdgcn_s_barrier();
    asm volatile("" ::: "memory");

    const u16* bq = &bbuf[cur][0];
    // A fragments from swizzled image
    bf16x8 a[2][3];
#pragma unroll
    for (int mf = 0; mf < 2; ++mf) {
      int y = mf * 32 + (l & 31);
      int rr = y + dy;
      const u16* base = imgp + vsw * 5504 + rr * 64;
      int sw = (rr & 7) << 3;
#pragma unroll
      for (int ks = 0; ks < 3; ++ks) {
        int c = (ks * 16 + (l >> 5) * 8) ^ sw;
        a[mf][ks] = *(const bf16x8*)(base + c);
      }
    }
#pragma unroll
    for (int nf = 0; nf < 4; ++nf) {
#pragma unroll
      for (int ks = 0; ks < 3; ++ks) {
        bf16x8 bfr = *(const bf16x8*)(bq + boff[nf][ks]);
        acc[0][nf] = __builtin_amdgcn_mfma_f32_32x32x16_bf16(a[0][ks], bfr, acc[0][nf], 0, 0, 0);
        acc[1][nf] = __builtin_amdgcn_mfma_f32_32x32x16_bf16(a[1][ks], bfr, acc[1][nf], 0, 0, 0);
      }
    }
    asm volatile("" ::: "memory");
    __builtin_amdgcn_s_barrier();
  }
#undef STAGE_B

  // epilogue: Lp[pos][v*16+k] bf16
  int v = vbase + vsw;
#pragma unroll
  for (int mf = 0; mf < 2; ++mf) {
#pragma unroll
    for (int nf = 0; nf < 4; ++nf) {
      int n = wn + nf * 32 + (l & 31);
      int x = x0g + (n >> 4), kch = n & 15;
#pragma unroll
      for (int r = 0; r < 16; ++r) {
        int y = mf * 32 + (r & 3) + 8 * (r >> 2) + 4 * (l >> 5);
        lp[(size_t)(y * 64 + x) * 1024 + v * 16 + kch] = (__bf16)acc[mf][nf][r];
      }
    }
  }
}

// ------------------------------------------------------------------
// Kernel D: Y[b][pos][h*64+v] = sum_k q[pos][h*16+k]*(LcB[k][v] + Lp[pos][v*16+k])
// ------------------------------------------------------------------
__global__ __launch_bounds__(256) void kD(const char* ws, float* out, int b0) {
  int t = threadIdx.x;
  int h = t >> 6, v = t & 63;
  int bb = blockIdx.x >> 6, pt = blockIdx.x & 63;
  int b = b0 + bb;
  const __bf16* qp = (const __bf16*)(ws + QP_OFF) + (size_t)b * 4096 * 64;
  const __bf16* lp = (const __bf16*)(ws + LP_OFF) + (size_t)bb * 4194304;
  const float* lcb = (const float*)(ws + LCB_OFF) + b * 1024;
  float lc[16];
#pragma unroll
  for (int i = 0; i < 16; ++i) lc[i] = lcb[i * 64 + v];
  int p0 = pt * 64;
  for (int pp = 0; pp < 64; ++pp) {
    int p = p0 + pp;
    const __bf16* qrow = qp + (size_t)p * 64 + h * 16;
    const __bf16* lrow = lp + (size_t)p * 1024 + v * 16;
    bf16x8 q0 = *(const bf16x8*)qrow;
    bf16x8 q1 = *(const bf16x8*)(qrow + 8);
    bf16x8 l0 = *(const bf16x8*)lrow;
    bf16x8 l1 = *(const bf16x8*)(lrow + 8);
    float sum = 0.f;
#pragma unroll
    for (int i = 0; i < 8; ++i) {
      sum += (float)q0[i] * (lc[i] + (float)l0[i]);
      sum += (float)q1[i] * (lc[8 + i] + (float)l1[i]);
    }
    out[((size_t)b * 4096 + p) * 256 + t] = sum;
  }
}

extern "C" void kernel_launch(void* const* d_in, const int* in_sizes, int n_in,
                              void* d_out, int out_size, void* d_ws, size_t ws_size,
                              hipStream_t stream) {
  const float* x   = (const float*)d_in[0];
  const float* Wq  = (const float*)d_in[1];
  const float* Wk  = (const float*)d_in[2];
  const float* Wv  = (const float*)d_in[3];
  const float* gq  = (const float*)d_in[4];
  const float* bq  = (const float*)d_in[5];
  const float* mq  = (const float*)d_in[6];
  const float* vq  = (const float*)d_in[7];
  const float* gv  = (const float*)d_in[8];
  const float* bv  = (const float*)d_in[9];
  const float* mv  = (const float*)d_in[10];
  const float* vvr = (const float*)d_in[11];
  const float* pw  = (const float*)d_in[12];
  const float* pb  = (const float*)d_in[13];
  char* ws = (char*)d_ws;
  float* out = (float*)d_out;

  hipLaunchKernelGGL(kP, dim3(24), dim3(256), 0, stream,
                     Wq, Wk, Wv, gq, bq, mq, vq, gv, bv, mv, vvr, pw, ws);
  hipLaunchKernelGGL(kA, dim3(256), dim3(256), 0, stream, x, ws);
  hipLaunchKernelGGL(kB1, dim3(256), dim3(256), 0, stream, ws);
  hipLaunchKernelGGL(kB2, dim3(1024), dim3(256), 0, stream, ws, pb);

  size_t avail = ws_size > LP_OFF ? ws_size - LP_OFF : 0;
  int nb = (int)(avail / LP_PER_B);
  if (nb < 1) nb = 1;
  if (nb > 16) nb = 16;
  for (int b0 = 0; b0 < 16; b0 += nb) {
    int cur = (16 - b0 < nb) ? 16 - b0 : nb;
    hipLaunchKernelGGL(kC, dim3(cur * 64), dim3(512), 0, stream, ws, b0);
    hipLaunchKernelGGL(kD, dim3(cur * 64), dim3(256), 0, stream, ws, out, b0);
  }
}

// Round 4
// 274.845 us; speedup vs baseline: 4.7106x; 1.0011x over previous
//
#include <hip/hip_runtime.h>
#include <stdint.h>

typedef __bf16 bf16x8 __attribute__((ext_vector_type(8)));
typedef float  f32x4  __attribute__((ext_vector_type(4)));
typedef float  f32x16 __attribute__((ext_vector_type(16)));
typedef unsigned short u16;

// ---- workspace layout (bytes) ----
#define WCT_OFF   0u          // 144*256 bf16 = 73728   (W^T, fused Wq|Wk|Wv)
#define SC_OFF    73728u      // 144 f32 BN scale
#define SH_OFF    74304u      // 144 f32 BN shift
#define BST_OFF   75008u      // 23 * 12288 bf16 = 565248 (banded conv B, frag-lane order)
#define MSUM_OFF  640256u     // 16*16*2 f32 (softmax max, 1/sum)
#define LCB_OFF   642304u     // 16*16*64 f32 (Lc + pos_b)
#define QP_OFF    707840u     // 16*4096*64 bf16 (q, BN'd, [b][pos][ch])
#define KT_OFF    9096448u    // 16*16*4096 bf16 (k, [b][ch][pos])
#define VT_OFF    11193600u   // 16*64*4096 bf16 (v, BN'd, [b][ch][pos] = per-v image)
#define LP_OFF    19582208u   // Lp bf16 [bchunk][pos][v*16+k], 8388608 B per b
#define LP_PER_B  8388608u

// ------------------------------------------------------------------
// Kernel P: precompute WcT (bf16), BN affine, banded conv B matrices
// ------------------------------------------------------------------
__global__ void kP(const float* Wq, const float* Wk, const float* Wv,
                   const float* gq, const float* bq, const float* mq, const float* vq,
                   const float* gv, const float* bv, const float* mv, const float* vvar,
                   const float* pw, char* ws) {
  int t = threadIdx.x;
  if (blockIdx.x == 0) {
    __bf16* wct = (__bf16*)(ws + WCT_OFF);
    for (int i = 0; i < 144; ++i) {
      int n = i, c = t;
      float val;
      if (n < 64)      val = Wq[c * 64 + n];
      else if (n < 80) val = Wk[c * 16 + (n - 64)];
      else             val = Wv[c * 64 + (n - 80)];
      wct[n * 256 + c] = (__bf16)val;
    }
    if (t < 144) {
      float s, sh;
      if (t < 64)      { s = gq[t] * rsqrtf(vq[t] + 1e-3f); sh = bq[t] - mq[t] * s; }
      else if (t < 80) { s = 1.f; sh = 0.f; }
      else { int i = t - 80; s = gv[i] * rsqrtf(vvar[i] + 1e-3f); sh = bv[i] - mv[i] * s; }
      ((float*)(ws + SC_OFF))[t] = s;
      ((float*)(ws + SH_OFF))[t] = sh;
    }
  } else {
    int dy = blockIdx.x - 1;               // 0..22
    __bf16* bst = (__bf16*)(ws + BST_OFF) + dy * 12288;
    for (int i = 0; i < 48; ++i) {
      int idx = i * 256 + t;               // < 12288
      int nt = idx / 1536, r1 = idx % 1536;
      int ks = r1 / 512,   r2 = r1 % 512;
      int l = r2 >> 3, e = r2 & 7;
      int j = ks * 16 + (l >> 5) * 8 + e;  // K index 0..47
      int n = nt * 32 + (l & 31);          // N index 0..255
      int xr = n >> 4, kch = n & 15;
      int dxw = j - xr - 5;                // img col = x + dxw - 11
      float val = (dxw >= 0 && dxw < 23) ? pw[(dy * 23 + dxw) * 16 + kch] : 0.f;
      bst[idx] = (__bf16)val;
    }
  }
}

// ------------------------------------------------------------------
// Kernel A: fused q/k/v projections (M=65536,K=256,N=144) + BN, MFMA 16x16x32
// q-part stored via LDS transpose -> dense bf16x8 global stores.
// ------------------------------------------------------------------
__global__ __launch_bounds__(256) void kA(const float* x, char* ws) {
  __shared__ __align__(16) u16 qlds[256 * 72];   // 256 pos x 64ch (pad 72), 36864B
  int t = threadIdx.x, w = t >> 6, l = t & 63;
  int m0 = blockIdx.x * 256;
  int b = m0 >> 12;
  int posb = m0 & 4095;
  const __bf16* wct = (const __bf16*)(ws + WCT_OFF);
  const float* sc = (const float*)(ws + SC_OFF);
  const float* sh = (const float*)(ws + SH_OFF);
  __bf16* qp = (__bf16*)(ws + QP_OFF);
  __bf16* kt = (__bf16*)(ws + KT_OFF);
  __bf16* vt = (__bf16*)(ws + VT_OFF);

  int rl = l & 15;      // A row / B col / C col within frag
  int kg = l >> 4;      // k-group 0..3

  f32x4 acc[4][9];
#pragma unroll
  for (int mf = 0; mf < 4; ++mf)
#pragma unroll
    for (int nf = 0; nf < 9; ++nf)
#pragma unroll
      for (int q = 0; q < 4; ++q) acc[mf][nf][q] = 0.f;

  for (int ks = 0; ks < 8; ++ks) {
    bf16x8 a[4];
#pragma unroll
    for (int mf = 0; mf < 4; ++mf) {
      int m = m0 + w * 64 + mf * 16 + rl;
      const float* xp = x + m * 256 + ks * 32 + kg * 8;
      f32x4 v0 = *(const f32x4*)xp;
      f32x4 v1 = *(const f32x4*)(xp + 4);
      bf16x8 av;
      av[0] = (__bf16)v0[0]; av[1] = (__bf16)v0[1]; av[2] = (__bf16)v0[2]; av[3] = (__bf16)v0[3];
      av[4] = (__bf16)v1[0]; av[5] = (__bf16)v1[1]; av[6] = (__bf16)v1[2]; av[7] = (__bf16)v1[3];
      a[mf] = av;
    }
#pragma unroll
    for (int nf = 0; nf < 9; ++nf) {
      bf16x8 bfr = *(const bf16x8*)(wct + (nf * 16 + rl) * 256 + ks * 32 + kg * 8);
#pragma unroll
      for (int mf = 0; mf < 4; ++mf)
        acc[mf][nf] = __builtin_amdgcn_mfma_f32_16x16x32_bf16(a[mf], bfr, acc[mf][nf], 0, 0, 0);
    }
  }

#pragma unroll
  for (int nf = 0; nf < 9; ++nf) {
    int ch = nf * 16 + rl;
    float s = sc[ch], shv = sh[ch];
#pragma unroll
    for (int mf = 0; mf < 4; ++mf) {
      int pbase = w * 64 + mf * 16 + kg * 4;   // pos within block
      union { __bf16 h[4]; uint2 u; } pk;
#pragma unroll
      for (int r = 0; r < 4; ++r) pk.h[r] = (__bf16)(acc[mf][nf][r] * s + shv);
      if (ch < 64) {
#pragma unroll
        for (int r = 0; r < 4; ++r)
          qlds[(pbase + r) * 72 + ch] = ((u16*)&pk.h[r])[0];
      } else if (ch < 80) {
        *(uint2*)(kt + (size_t)(b * 16 + ch - 64) * 4096 + posb + pbase) = pk.u;
      } else {
        *(uint2*)(vt + (size_t)(b * 64 + ch - 80) * 4096 + posb + pbase) = pk.u;
      }
    }
  }
  __syncthreads();
  // dense readback: 2048 chunks of 8 bf16
#pragma unroll
  for (int i = 0; i < 8; ++i) {
    int chunk = t + i * 256;
    int row = chunk >> 3, seg = chunk & 7;
    bf16x8 vq_ = *(const bf16x8*)(qlds + row * 72 + seg * 8);
    *(bf16x8*)(qp + (size_t)(b * 4096 + posb + row) * 64 + seg * 8) = vq_;
  }
}

// ------------------------------------------------------------------
// Kernel B1: per (b, k-channel) softmax max & 1/sum over 4096 positions
// ------------------------------------------------------------------
__global__ void kB1(char* ws) {
  __shared__ float red[256];
  int t = threadIdx.x;
  int b = blockIdx.x >> 4, kk = blockIdx.x & 15;
  const __bf16* kt = (const __bf16*)(ws + KT_OFF) + (size_t)(b * 16 + kk) * 4096;
  float v[16];
  bf16x8 c0 = *(const bf16x8*)(kt + t * 16);
  bf16x8 c1 = *(const bf16x8*)(kt + t * 16 + 8);
#pragma unroll
  for (int i = 0; i < 8; ++i) { v[i] = (float)c0[i]; v[8 + i] = (float)c1[i]; }
  float mx = v[0];
#pragma unroll
  for (int i = 1; i < 16; ++i) mx = fmaxf(mx, v[i]);
  red[t] = mx; __syncthreads();
  for (int s = 128; s > 0; s >>= 1) { if (t < s) red[t] = fmaxf(red[t], red[t + s]); __syncthreads(); }
  mx = red[0]; __syncthreads();
  float se = 0.f;
#pragma unroll
  for (int i = 0; i < 16; ++i) se += expf(v[i] - mx);
  red[t] = se; __syncthreads();
  for (int s = 128; s > 0; s >>= 1) { if (t < s) red[t] += red[t + s]; __syncthreads(); }
  if (t == 0) {
    float* ms = (float*)(ws + MSUM_OFF);
    ms[(b * 16 + kk) * 2] = mx;
    ms[(b * 16 + kk) * 2 + 1] = 1.f / red[0];
  }
}

// ------------------------------------------------------------------
// Kernel B2: LcB[b][k][v] = sum_n softmax(k)[n]*v[v][n] + pos_b[k]
// ------------------------------------------------------------------
__global__ __launch_bounds__(256) void kB2(char* ws, const float* pos_b) {
  __shared__ float red[16][256];
  int t = threadIdx.x;
  int b = blockIdx.x >> 6, v = blockIdx.x & 63;
  const __bf16* kt = (const __bf16*)(ws + KT_OFF) + (size_t)b * 16 * 4096;
  const __bf16* vt = (const __bf16*)(ws + VT_OFF) + (size_t)(b * 64 + v) * 4096;
  const float* ms = (const float*)(ws + MSUM_OFF) + b * 32;
  float mx[16];
#pragma unroll
  for (int i = 0; i < 16; ++i) mx[i] = ms[2 * i];
  float acc[16];
#pragma unroll
  for (int i = 0; i < 16; ++i) acc[i] = 0.f;
  for (int c = 0; c < 16; ++c) {
    int p = c * 256 + t;
    float vv = (float)vt[p];
#pragma unroll
    for (int i = 0; i < 16; ++i)
      acc[i] += expf((float)kt[i * 4096 + p] - mx[i]) * vv;
  }
#pragma unroll
  for (int i = 0; i < 16; ++i) red[i][t] = acc[i];
  __syncthreads();
  for (int s = 128; s > 0; s >>= 1) {
    if (t < s) {
#pragma unroll
      for (int i = 0; i < 16; ++i) red[i][t] += red[i][t + s];
    }
    __syncthreads();
  }
  if (t < 16) {
    float* lcb = (float*)(ws + LCB_OFF);
    lcb[(b * 16 + t) * 64 + v] = red[t][0] * ms[2 * t + 1] + pos_b[t];
  }
}

// ------------------------------------------------------------------
// Kernel C: 23x23 conv as banded GEMM, MFMA 32x32x16 bf16.
// Grid = (b, v-pair of 2, x-tile of 16). M=128 (2v x 64y), N=256 (16x x 16k).
// 4 waves/block, 71KB LDS -> 2 independent blocks/CU (barrier overlap).
// dy loop: B double-buffered via global_load_lds, counted vmcnt(6).
// ------------------------------------------------------------------
__global__ __launch_bounds__(256, 2) void kC(char* ws, int b0) {
  __shared__ __align__(16) u16 imgp[2 * 86 * 64];   // [vs][rr][64], swizzled, 22016B
  __shared__ __align__(16) u16 bbuf[2][12288];      // double-buffered B, 24576B each
  int t = threadIdx.x, w = t >> 6, l = t & 63;
  int bb = blockIdx.x >> 7;
  int b = b0 + bb;
  int rest = blockIdx.x & 127;
  int vg = rest >> 2, xt = rest & 3;
  int vbase = vg * 2, x0g = xt * 16;
  const __bf16* vt = (const __bf16*)(ws + VT_OFF);
  const char* bstc = (const char*)(ws + BST_OFF);
  __bf16* lp = (__bf16*)(ws + LP_OFF) + (size_t)bb * 4194304;

  // zero the padded image buffer (1376 x 16B)
  bf16x8 z;
#pragma unroll
  for (int q = 0; q < 8; ++q) z[q] = (__bf16)0.f;
#pragma unroll
  for (int i = 0; i < 6; ++i) {
    int idx = t + i * 256;
    if (idx < 1376) ((bf16x8*)imgp)[idx] = z;
  }
  __syncthreads();
  // stage interior: 2 vs x 64 rows x 6 chunks = 768 slots
#pragma unroll
  for (int i = 0; i < 3; ++i) {
    int slot = t + i * 256;
    int vs = slot / 384, rem = slot % 384;
    int y = rem / 6, c0 = (rem % 6) * 8;
    int gx = x0g - 16 + c0;
    if (gx >= 0 && gx < 64) {
      bf16x8 val = *(const bf16x8*)(vt + (size_t)(b * 64 + vbase + vs) * 4096 + y * 64 + gx);
      int rr = 11 + y;
      *(bf16x8*)(imgp + vs * 5504 + rr * 64 + (c0 ^ ((rr & 7) << 3))) = val;
    }
  }
  __syncthreads();

  int n_half = w & 1, v_local = w >> 1;
  int wn = n_half * 128;
  // B fragment offsets (u16) within a bbuf
  int boff[4][3];
#pragma unroll
  for (int nf = 0; nf < 4; ++nf) {
    int nt = n_half * 4 + nf;
#pragma unroll
    for (int ks = 0; ks < 3; ++ks)
      boff[nf][ks] = ((nt * 3 + ks) * 64 + l) * 8;
  }

  f32x16 acc[2][4];
#pragma unroll
  for (int mf = 0; mf < 2; ++mf)
#pragma unroll
    for (int nf = 0; nf < 4; ++nf)
#pragma unroll
      for (int q = 0; q < 16; ++q) acc[mf][nf][q] = 0.f;

  // async stage: 6 x 16B per thread, linear frag-order (wave-uniform base + lane*16)
#define STAGE_B(bufsel, dyv) do {                                              \
    const char* gsrc = bstc + (dyv) * 24576 + (w * 64 + l) * 16;               \
    char* ldsb = (char*)&bbuf[(bufsel)][0] + w * 1024;                         \
    _Pragma("unroll")                                                          \
    for (int i_ = 0; i_ < 6; ++i_)                                             \
      __builtin_amdgcn_global_load_lds(                                        \
        (const __attribute__((address_space(1))) void*)(gsrc + i_ * 4096),     \
        (__attribute__((address_space(3))) void*)(ldsb + i_ * 4096), 16, 0, 0);\
  } while (0)

  STAGE_B(0, 0);

  for (int dy = 0; dy < 23; ++dy) {
    int cur = dy & 1;
    if (dy < 22) {
      STAGE_B(cur ^ 1, dy + 1);
      asm volatile("s_waitcnt vmcnt(6)" ::: "memory");
    } else {
      asm volatile("s_waitcnt vmcnt(0)" ::: "memory");
    }
    __builtin_amdgcn_s_barrier();
    asm volatile("" ::: "memory");

    const u16* bq = &bbuf[cur][0];
    // A fragments from swizzled image
    bf16x8 a[2][3];
#pragma unroll
    for (int mf = 0; mf < 2; ++mf) {
      int y = mf * 32 + (l & 31);
      int rr = y + dy;
      const u16* base = imgp + v_local * 5504 + rr * 64;
      int sw = (rr & 7) << 3;
#pragma unroll
      for (int ks = 0; ks < 3; ++ks) {
        int c = (ks * 16 + (l >> 5) * 8) ^ sw;
        a[mf][ks] = *(const bf16x8*)(base + c);
      }
    }
#pragma unroll
    for (int nf = 0; nf < 4; ++nf) {
#pragma unroll
      for (int ks = 0; ks < 3; ++ks) {
        bf16x8 bfr = *(const bf16x8*)(bq + boff[nf][ks]);
        acc[0][nf] = __builtin_amdgcn_mfma_f32_32x32x16_bf16(a[0][ks], bfr, acc[0][nf], 0, 0, 0);
        acc[1][nf] = __builtin_amdgcn_mfma_f32_32x32x16_bf16(a[1][ks], bfr, acc[1][nf], 0, 0, 0);
      }
    }
    asm volatile("" ::: "memory");
    __builtin_amdgcn_s_barrier();
  }
#undef STAGE_B

  // epilogue: Lp[pos][v*16+k] bf16
  int v = vbase + v_local;
#pragma unroll
  for (int mf = 0; mf < 2; ++mf) {
#pragma unroll
    for (int nf = 0; nf < 4; ++nf) {
      int n = wn + nf * 32 + (l & 31);
      int x = x0g + (n >> 4), kch = n & 15;
#pragma unroll
      for (int r = 0; r < 16; ++r) {
        int y = mf * 32 + (r & 3) + 8 * (r >> 2) + 4 * (l >> 5);
        lp[(size_t)(y * 64 + x) * 1024 + v * 16 + kch] = (__bf16)acc[mf][nf][r];
      }
    }
  }
}

// ------------------------------------------------------------------
// Kernel D: Y[b][pos][h*64+v] = sum_k q[pos][h*16+k]*(LcB[k][v] + Lp[pos][v*16+k])
// ------------------------------------------------------------------
__global__ __launch_bounds__(256) void kD(const char* ws, float* out, int b0) {
  int t = threadIdx.x;
  int h = t >> 6, v = t & 63;
  int bb = blockIdx.x >> 6, pt = blockIdx.x & 63;
  int b = b0 + bb;
  const __bf16* qp = (const __bf16*)(ws + QP_OFF) + (size_t)b * 4096 * 64;
  const __bf16* lp = (const __bf16*)(ws + LP_OFF) + (size_t)bb * 4194304;
  const float* lcb = (const float*)(ws + LCB_OFF) + b * 1024;
  float lc[16];
#pragma unroll
  for (int i = 0; i < 16; ++i) lc[i] = lcb[i * 64 + v];
  int p0 = pt * 64;
  for (int pp = 0; pp < 64; ++pp) {
    int p = p0 + pp;
    const __bf16* qrow = qp + (size_t)p * 64 + h * 16;
    const __bf16* lrow = lp + (size_t)p * 1024 + v * 16;
    bf16x8 q0 = *(const bf16x8*)qrow;
    bf16x8 q1 = *(const bf16x8*)(qrow + 8);
    bf16x8 l0 = *(const bf16x8*)lrow;
    bf16x8 l1 = *(const bf16x8*)(lrow + 8);
    float sum = 0.f;
#pragma unroll
    for (int i = 0; i < 8; ++i) {
      sum += (float)q0[i] * (lc[i] + (float)l0[i]);
      sum += (float)q1[i] * (lc[8 + i] + (float)l1[i]);
    }
    out[((size_t)b * 4096 + p) * 256 + t] = sum;
  }
}

extern "C" void kernel_launch(void* const* d_in, const int* in_sizes, int n_in,
                              void* d_out, int out_size, void* d_ws, size_t ws_size,
                              hipStream_t stream) {
  const float* x   = (const float*)d_in[0];
  const float* Wq  = (const float*)d_in[1];
  const float* Wk  = (const float*)d_in[2];
  const float* Wv  = (const float*)d_in[3];
  const float* gq  = (const float*)d_in[4];
  const float* bq  = (const float*)d_in[5];
  const float* mq  = (const float*)d_in[6];
  const float* vq  = (const float*)d_in[7];
  const float* gv  = (const float*)d_in[8];
  const float* bv  = (const float*)d_in[9];
  const float* mv  = (const float*)d_in[10];
  const float* vvr = (const float*)d_in[11];
  const float* pw  = (const float*)d_in[12];
  const float* pb  = (const float*)d_in[13];
  char* ws = (char*)d_ws;
  float* out = (float*)d_out;

  hipLaunchKernelGGL(kP, dim3(24), dim3(256), 0, stream,
                     Wq, Wk, Wv, gq, bq, mq, vq, gv, bv, mv, vvr, pw, ws);
  hipLaunchKernelGGL(kA, dim3(256), dim3(256), 0, stream, x, ws);
  hipLaunchKernelGGL(kB1, dim3(256), dim3(256), 0, stream, ws);
  hipLaunchKernelGGL(kB2, dim3(1024), dim3(256), 0, stream, ws, pb);

  size_t avail = ws_size > LP_OFF ? ws_size - LP_OFF : 0;
  int nb = (int)(avail / LP_PER_B);
  if (nb < 1) nb = 1;
  if (nb > 16) nb = 16;
  for (int b0 = 0; b0 < 16; b0 += nb) {
    int cur = (16 - b0 < nb) ? 16 - b0 : nb;
    hipLaunchKernelGGL(kC, dim3(cur * 128), dim3(256), 0, stream, ws, b0);
    hipLaunchKernelGGL(kD, dim3(cur * 64), dim3(256), 0, stream, ws, out, b0);
  }
}

// Round 5
// 241.735 us; speedup vs baseline: 5.3559x; 1.1370x over previous
//
#include <hip/hip_runtime.h>
#include <stdint.h>

typedef __bf16 bf16x8 __attribute__((ext_vector_type(8)));
typedef float  f32x4  __attribute__((ext_vector_type(4)));
typedef float  f32x16 __attribute__((ext_vector_type(16)));
typedef unsigned short u16;

// ---- workspace layout (bytes) ----
#define WCT_OFF   0u          // 144*256 bf16 = 73728   (W^T, fused Wq|Wk|Wv)
#define SC_OFF    73728u      // 144 f32 BN scale
#define SH_OFF    74304u      // 144 f32 BN shift
#define BST_OFF   75008u      // 23 * 16384 bf16-bytes (2-window B frags, frag-lane order)
#define MSUM_OFF  640256u     // 16*16*2 f32 (softmax max, 1/sum)
#define LCB_OFF   642304u     // 16*16*64 f32 (Lc + pos_b)
#define QP_OFF    707840u     // 16*4096*64 bf16 (q, BN'd, [b][pos][ch])
#define KT_OFF    9096448u    // 16*16*4096 bf16 (k, [b][ch][pos])
#define VT_OFF    11193600u   // 16*64*4096 bf16 (v, BN'd, [b][ch][pos] = per-v image)
#define LP_OFF    19582208u   // Lp bf16 [bchunk][pos][v*16+k], 8388608 B per b
#define LP_PER_B  8388608u

// ------------------------------------------------------------------
// Kernel P: precompute WcT (bf16), BN affine, 2-window conv B fragments.
// B2[dy][nt][w2][lane][e]: value w[dy, j - xr - 5, kch], j = o1(nt) + w2*16
// + (lane>>5)*8 + e, with o1(nt) = floor8(2nt+5); n = nt*32 + (lane&31),
// xr = n>>4, kch = n&15. Zero outside dxw in [0,23).
// ------------------------------------------------------------------
__global__ void kP(const float* Wq, const float* Wk, const float* Wv,
                   const float* gq, const float* bq, const float* mq, const float* vq,
                   const float* gv, const float* bv, const float* mv, const float* vvar,
                   const float* pw, char* ws) {
  int t = threadIdx.x;
  if (blockIdx.x == 0) {
    __bf16* wct = (__bf16*)(ws + WCT_OFF);
    for (int i = 0; i < 144; ++i) {
      int n = i, c = t;
      float val;
      if (n < 64)      val = Wq[c * 64 + n];
      else if (n < 80) val = Wk[c * 16 + (n - 64)];
      else             val = Wv[c * 64 + (n - 80)];
      wct[n * 256 + c] = (__bf16)val;
    }
    if (t < 144) {
      float s, sh;
      if (t < 64)      { s = gq[t] * rsqrtf(vq[t] + 1e-3f); sh = bq[t] - mq[t] * s; }
      else if (t < 80) { s = 1.f; sh = 0.f; }
      else { int i = t - 80; s = gv[i] * rsqrtf(vvar[i] + 1e-3f); sh = bv[i] - mv[i] * s; }
      ((float*)(ws + SC_OFF))[t] = s;
      ((float*)(ws + SH_OFF))[t] = sh;
    }
  } else {
    int dy = blockIdx.x - 1;               // 0..22
    __bf16* bst = (__bf16*)(ws + BST_OFF) + dy * 8192;
    for (int i = 0; i < 32; ++i) {
      int idx = i * 256 + t;               // < 8192
      int nt = idx >> 10;
      int w2 = (idx >> 9) & 1;
      int l  = (idx >> 3) & 63;
      int e  = idx & 7;
      int n  = nt * 32 + (l & 31);
      int xr = n >> 4, kch = n & 15;
      int o1 = (2 * nt + 5) & ~7;
      int j  = o1 + w2 * 16 + (l >> 5) * 8 + e;
      int dxw = j - xr - 5;
      float val = (dxw >= 0 && dxw < 23) ? pw[(dy * 23 + dxw) * 16 + kch] : 0.f;
      bst[idx] = (__bf16)val;
    }
  }
}

// ------------------------------------------------------------------
// Kernel A: fused q/k/v projections (M=65536,K=256,N=144) + BN, MFMA 16x16x32
// q-part stored via LDS transpose -> dense bf16x8 global stores.
// ------------------------------------------------------------------
__global__ __launch_bounds__(256) void kA(const float* x, char* ws) {
  __shared__ __align__(16) u16 qlds[256 * 72];   // 256 pos x 64ch (pad 72), 36864B
  int t = threadIdx.x, w = t >> 6, l = t & 63;
  int m0 = blockIdx.x * 256;
  int b = m0 >> 12;
  int posb = m0 & 4095;
  const __bf16* wct = (const __bf16*)(ws + WCT_OFF);
  const float* sc = (const float*)(ws + SC_OFF);
  const float* sh = (const float*)(ws + SH_OFF);
  __bf16* qp = (__bf16*)(ws + QP_OFF);
  __bf16* kt = (__bf16*)(ws + KT_OFF);
  __bf16* vt = (__bf16*)(ws + VT_OFF);

  int rl = l & 15;      // A row / B col / C col within frag
  int kg = l >> 4;      // k-group 0..3

  f32x4 acc[4][9];
#pragma unroll
  for (int mf = 0; mf < 4; ++mf)
#pragma unroll
    for (int nf = 0; nf < 9; ++nf)
#pragma unroll
      for (int q = 0; q < 4; ++q) acc[mf][nf][q] = 0.f;

  for (int ks = 0; ks < 8; ++ks) {
    bf16x8 a[4];
#pragma unroll
    for (int mf = 0; mf < 4; ++mf) {
      int m = m0 + w * 64 + mf * 16 + rl;
      const float* xp = x + m * 256 + ks * 32 + kg * 8;
      f32x4 v0 = *(const f32x4*)xp;
      f32x4 v1 = *(const f32x4*)(xp + 4);
      bf16x8 av;
      av[0] = (__bf16)v0[0]; av[1] = (__bf16)v0[1]; av[2] = (__bf16)v0[2]; av[3] = (__bf16)v0[3];
      av[4] = (__bf16)v1[0]; av[5] = (__bf16)v1[1]; av[6] = (__bf16)v1[2]; av[7] = (__bf16)v1[3];
      a[mf] = av;
    }
#pragma unroll
    for (int nf = 0; nf < 9; ++nf) {
      bf16x8 bfr = *(const bf16x8*)(wct + (nf * 16 + rl) * 256 + ks * 32 + kg * 8);
#pragma unroll
      for (int mf = 0; mf < 4; ++mf)
        acc[mf][nf] = __builtin_amdgcn_mfma_f32_16x16x32_bf16(a[mf], bfr, acc[mf][nf], 0, 0, 0);
    }
  }

#pragma unroll
  for (int nf = 0; nf < 9; ++nf) {
    int ch = nf * 16 + rl;
    float s = sc[ch], shv = sh[ch];
#pragma unroll
    for (int mf = 0; mf < 4; ++mf) {
      int pbase = w * 64 + mf * 16 + kg * 4;   // pos within block
      union { __bf16 h[4]; uint2 u; } pk;
#pragma unroll
      for (int r = 0; r < 4; ++r) pk.h[r] = (__bf16)(acc[mf][nf][r] * s + shv);
      if (ch < 64) {
#pragma unroll
        for (int r = 0; r < 4; ++r)
          qlds[(pbase + r) * 72 + ch] = ((u16*)&pk.h[r])[0];
      } else if (ch < 80) {
        *(uint2*)(kt + (size_t)(b * 16 + ch - 64) * 4096 + posb + pbase) = pk.u;
      } else {
        *(uint2*)(vt + (size_t)(b * 64 + ch - 80) * 4096 + posb + pbase) = pk.u;
      }
    }
  }
  __syncthreads();
  // dense readback: 2048 chunks of 8 bf16
#pragma unroll
  for (int i = 0; i < 8; ++i) {
    int chunk = t + i * 256;
    int row = chunk >> 3, seg = chunk & 7;
    bf16x8 vq_ = *(const bf16x8*)(qlds + row * 72 + seg * 8);
    *(bf16x8*)(qp + (size_t)(b * 4096 + posb + row) * 64 + seg * 8) = vq_;
  }
}

// ------------------------------------------------------------------
// Kernel B1: per (b, k-channel) softmax max & 1/sum over 4096 positions
// ------------------------------------------------------------------
__global__ void kB1(char* ws) {
  __shared__ float red[256];
  int t = threadIdx.x;
  int b = blockIdx.x >> 4, kk = blockIdx.x & 15;
  const __bf16* kt = (const __bf16*)(ws + KT_OFF) + (size_t)(b * 16 + kk) * 4096;
  float v[16];
  bf16x8 c0 = *(const bf16x8*)(kt + t * 16);
  bf16x8 c1 = *(const bf16x8*)(kt + t * 16 + 8);
#pragma unroll
  for (int i = 0; i < 8; ++i) { v[i] = (float)c0[i]; v[8 + i] = (float)c1[i]; }
  float mx = v[0];
#pragma unroll
  for (int i = 1; i < 16; ++i) mx = fmaxf(mx, v[i]);
  red[t] = mx; __syncthreads();
  for (int s = 128; s > 0; s >>= 1) { if (t < s) red[t] = fmaxf(red[t], red[t + s]); __syncthreads(); }
  mx = red[0]; __syncthreads();
  float se = 0.f;
#pragma unroll
  for (int i = 0; i < 16; ++i) se += expf(v[i] - mx);
  red[t] = se; __syncthreads();
  for (int s = 128; s > 0; s >>= 1) { if (t < s) red[t] += red[t + s]; __syncthreads(); }
  if (t == 0) {
    float* ms = (float*)(ws + MSUM_OFF);
    ms[(b * 16 + kk) * 2] = mx;
    ms[(b * 16 + kk) * 2 + 1] = 1.f / red[0];
  }
}

// ------------------------------------------------------------------
// Kernel B2: LcB[b][k][v] = sum_n softmax(k)[n]*v[v][n] + pos_b[k]
// ------------------------------------------------------------------
__global__ __launch_bounds__(256) void kB2(char* ws, const float* pos_b) {
  __shared__ float red[16][256];
  int t = threadIdx.x;
  int b = blockIdx.x >> 6, v = blockIdx.x & 63;
  const __bf16* kt = (const __bf16*)(ws + KT_OFF) + (size_t)b * 16 * 4096;
  const __bf16* vt = (const __bf16*)(ws + VT_OFF) + (size_t)(b * 64 + v) * 4096;
  const float* ms = (const float*)(ws + MSUM_OFF) + b * 32;
  float mx[16];
#pragma unroll
  for (int i = 0; i < 16; ++i) mx[i] = ms[2 * i];
  float acc[16];
#pragma unroll
  for (int i = 0; i < 16; ++i) acc[i] = 0.f;
  for (int c = 0; c < 16; ++c) {
    int p = c * 256 + t;
    float vv = (float)vt[p];
#pragma unroll
    for (int i = 0; i < 16; ++i)
      acc[i] += expf((float)kt[i * 4096 + p] - mx[i]) * vv;
  }
#pragma unroll
  for (int i = 0; i < 16; ++i) red[i][t] = acc[i];
  __syncthreads();
  for (int s = 128; s > 0; s >>= 1) {
    if (t < s) {
#pragma unroll
      for (int i = 0; i < 16; ++i) red[i][t] += red[i][t + s];
    }
    __syncthreads();
  }
  if (t < 16) {
    float* lcb = (float*)(ws + LCB_OFF);
    lcb[(b * 16 + t) * 64 + v] = red[t][0] * ms[2 * t + 1] + pos_b[t];
  }
}

// ------------------------------------------------------------------
// Kernel C: 23x23 conv as banded GEMM, 2 aligned K=16 windows per n-tile.
// Grid = (b, v-pair, x-tile). M=128 (2v x 64y), N=256 (16x x 16k).
// Per dy: 16 MFMA/wave (vs 24 in the K=48 band), B triple-buffered via
// global_load_lds (16KB/dy), vmcnt(4) + ONE s_barrier per dy.
// ------------------------------------------------------------------
__global__ __launch_bounds__(256, 2) void kC(char* ws, int b0) {
  __shared__ __align__(16) u16 imgp[2 * 86 * 56];   // [vs][rr][56], 19264B
  __shared__ __align__(16) u16 bbuf[3][8192];       // triple-buffered B, 16384B each
  int t = threadIdx.x, w = t >> 6, l = t & 63;
  int bb = blockIdx.x >> 7;
  int b = b0 + bb;
  int rest = blockIdx.x & 127;
  int vg = rest >> 2, xt = rest & 3;
  int vbase = vg * 2, x0g = xt * 16;
  const __bf16* vt = (const __bf16*)(ws + VT_OFF);
  const char* bstc = (const char*)(ws + BST_OFF);
  __bf16* lp = (__bf16*)(ws + LP_OFF) + (size_t)bb * 4194304;

  int nh = w & 1, v_local = w >> 1;
  int hh = l >> 5;            // k-half
  int rr0 = l & 31;           // row within 32-row m-frag

  // zero the image buffer (1204 x 16B)
  bf16x8 z;
#pragma unroll
  for (int q = 0; q < 8; ++q) z[q] = (__bf16)0.f;
#pragma unroll
  for (int i = 0; i < 5; ++i) {
    int idx = t + i * 256;
    if (idx < 1204) ((bf16x8*)imgp)[idx] = z;
  }
  __syncthreads();
  // stage interior: rows 11..74 hold image rows y=0..63, logical col c ->
  // global x = x0g - 16 + c, c in [0,56)
#pragma unroll
  for (int i = 0; i < 4; ++i) {
    int slot = t + i * 256;            // < 896 = 2v * 64y * 7 chunks
    if (slot < 896) {
      int vs = slot / 448, rem = slot % 448;
      int y = rem / 7, c0 = (rem % 7) * 8;
      int gx = x0g - 16 + c0;
      if (gx >= 0 && gx < 64) {
        bf16x8 val = *(const bf16x8*)(vt + (size_t)(b * 64 + vbase + vs) * 4096 + y * 64 + gx);
        *(bf16x8*)(imgp + vs * 4816 + (11 + y) * 56 + c0) = val;
      }
    }
  }

  // per-lane B fragment offsets (u16) within one bbuf: [nt][w2][lane][8]
  int boff[4][2];
#pragma unroll
  for (int nf = 0; nf < 4; ++nf)
#pragma unroll
    for (int w2 = 0; w2 < 2; ++w2)
      boff[nf][w2] = (((nh * 4 + nf) * 2 + w2) * 64 + l) * 8;

  // per-mf A base (u16 index into imgp), advanced by 56 per dy
  int abase[2];
#pragma unroll
  for (int mf = 0; mf < 2; ++mf)
    abase[mf] = v_local * 4816 + (mf * 32 + rr0) * 56 + (nh + hh) * 8;

  f32x16 acc[2][4];
#pragma unroll
  for (int mf = 0; mf < 2; ++mf)
#pragma unroll
    for (int nf = 0; nf < 4; ++nf)
#pragma unroll
      for (int q = 0; q < 16; ++q) acc[mf][nf][q] = 0.f;

  // async stage: 4 x 16B per thread, linear frag-order.
  // LDS dest = wave-uniform base (HW adds lane*16); global src has + l*16.
#define STAGE_B(bufsel, dyv) do {                                              \
    const char* gsrc = bstc + (dyv) * 16384 + w * 1024 + l * 16;               \
    char* ldsb = (char*)&bbuf[0][0] + (bufsel) * 16384 + w * 1024;             \
    _Pragma("unroll")                                                          \
    for (int i_ = 0; i_ < 4; ++i_)                                             \
      __builtin_amdgcn_global_load_lds(                                        \
        (const __attribute__((address_space(1))) void*)(gsrc + i_ * 4096),     \
        (__attribute__((address_space(3))) void*)(ldsb + i_ * 4096), 16, 0, 0);\
  } while (0)

  STAGE_B(0, 0);
  __syncthreads();   // imgp staging complete (also covers bbuf[0] ordering via loop waits below)

  int cur = 0;
  for (int dy = 0; dy < 23; ++dy) {
    int nxt = cur + 1; if (nxt == 3) nxt = 0;
    if (dy < 22) {
      STAGE_B(nxt, dy + 1);
      asm volatile("s_waitcnt vmcnt(4)" ::: "memory");
    } else {
      asm volatile("s_waitcnt vmcnt(0)" ::: "memory");
    }
    __builtin_amdgcn_s_barrier();
    asm volatile("" ::: "memory");

    const u16* bq = &bbuf[0][0] + cur * 8192;
    // A fragments: 4 aligned 8-col windows per mf
    bf16x8 a[2][4];
#pragma unroll
    for (int mf = 0; mf < 2; ++mf) {
      const u16* base = imgp + abase[mf] + dy * 56;
#pragma unroll
      for (int i = 0; i < 4; ++i)
        a[mf][i] = *(const bf16x8*)(base + i * 8);
    }
#pragma unroll
    for (int w2 = 0; w2 < 2; ++w2) {
#pragma unroll
      for (int nf = 0; nf < 4; ++nf) {
        bf16x8 bfr = *(const bf16x8*)(bq + boff[nf][w2]);
        int ai = (nf >> 1) + 2 * w2;
        acc[0][nf] = __builtin_amdgcn_mfma_f32_32x32x16_bf16(a[0][ai], bfr, acc[0][nf], 0, 0, 0);
        acc[1][nf] = __builtin_amdgcn_mfma_f32_32x32x16_bf16(a[1][ai], bfr, acc[1][nf], 0, 0, 0);
      }
    }
    cur = nxt;
  }
#undef STAGE_B

  // epilogue: Lp[pos][v*16+k] bf16
  int v = vbase + v_local;
  int wn = nh * 128;
#pragma unroll
  for (int mf = 0; mf < 2; ++mf) {
#pragma unroll
    for (int nf = 0; nf < 4; ++nf) {
      int n = wn + nf * 32 + (l & 31);
      int x = x0g + (n >> 4), kch = n & 15;
#pragma unroll
      for (int r = 0; r < 16; ++r) {
        int y = mf * 32 + (r & 3) + 8 * (r >> 2) + 4 * (l >> 5);
        lp[(size_t)(y * 64 + x) * 1024 + v * 16 + kch] = (__bf16)acc[mf][nf][r];
      }
    }
  }
}

// ------------------------------------------------------------------
// Kernel D: Y[b][pos][h*64+v] = sum_k q[pos][h*16+k]*(LcB[k][v] + Lp[pos][v*16+k])
// ------------------------------------------------------------------
__global__ __launch_bounds__(256) void kD(const char* ws, float* out, int b0) {
  int t = threadIdx.x;
  int h = t >> 6, v = t & 63;
  int bb = blockIdx.x >> 6, pt = blockIdx.x & 63;
  int b = b0 + bb;
  const __bf16* qp = (const __bf16*)(ws + QP_OFF) + (size_t)b * 4096 * 64;
  const __bf16* lp = (const __bf16*)(ws + LP_OFF) + (size_t)bb * 4194304;
  const float* lcb = (const float*)(ws + LCB_OFF) + b * 1024;
  float lc[16];
#pragma unroll
  for (int i = 0; i < 16; ++i) lc[i] = lcb[i * 64 + v];
  int p0 = pt * 64;
  for (int pp = 0; pp < 64; ++pp) {
    int p = p0 + pp;
    const __bf16* qrow = qp + (size_t)p * 64 + h * 16;
    const __bf16* lrow = lp + (size_t)p * 1024 + v * 16;
    bf16x8 q0 = *(const bf16x8*)qrow;
    bf16x8 q1 = *(const bf16x8*)(qrow + 8);
    bf16x8 l0 = *(const bf16x8*)lrow;
    bf16x8 l1 = *(const bf16x8*)(lrow + 8);
    float sum = 0.f;
#pragma unroll
    for (int i = 0; i < 8; ++i) {
      sum += (float)q0[i] * (lc[i] + (float)l0[i]);
      sum += (float)q1[i] * (lc[8 + i] + (float)l1[i]);
    }
    out[((size_t)b * 4096 + p) * 256 + t] = sum;
  }
}

extern "C" void kernel_launch(void* const* d_in, const int* in_sizes, int n_in,
                              void* d_out, int out_size, void* d_ws, size_t ws_size,
                              hipStream_t stream) {
  const float* x   = (const float*)d_in[0];
  const float* Wq  = (const float*)d_in[1];
  const float* Wk  = (const float*)d_in[2];
  const float* Wv  = (const float*)d_in[3];
  const float* gq  = (const float*)d_in[4];
  const float* bq  = (const float*)d_in[5];
  const float* mq  = (const float*)d_in[6];
  const float* vq  = (const float*)d_in[7];
  const float* gv  = (const float*)d_in[8];
  const float* bv  = (const float*)d_in[9];
  const float* mv  = (const float*)d_in[10];
  const float* vvr = (const float*)d_in[11];
  const float* pw  = (const float*)d_in[12];
  const float* pb  = (const float*)d_in[13];
  char* ws = (char*)d_ws;
  float* out = (float*)d_out;

  hipLaunchKernelGGL(kP, dim3(24), dim3(256), 0, stream,
                     Wq, Wk, Wv, gq, bq, mq, vq, gv, bv, mv, vvr, pw, ws);
  hipLaunchKernelGGL(kA, dim3(256), dim3(256), 0, stream, x, ws);
  hipLaunchKernelGGL(kB1, dim3(256), dim3(256), 0, stream, ws);
  hipLaunchKernelGGL(kB2, dim3(1024), dim3(256), 0, stream, ws, pb);

  size_t avail = ws_size > LP_OFF ? ws_size - LP_OFF : 0;
  int nb = (int)(avail / LP_PER_B);
  if (nb < 1) nb = 1;
  if (nb > 16) nb = 16;
  for (int b0 = 0; b0 < 16; b0 += nb) {
    int cur = (16 - b0 < nb) ? 16 - b0 : nb;
    hipLaunchKernelGGL(kC, dim3(cur * 128), dim3(256), 0, stream, ws, b0);
    hipLaunchKernelGGL(kD, dim3(cur * 64), dim3(256), 0, stream, ws, out, b0);
  }
}

// Round 6
// 234.167 us; speedup vs baseline: 5.5290x; 1.0323x over previous
//
#include <hip/hip_runtime.h>
#include <stdint.h>

typedef __bf16 bf16x8 __attribute__((ext_vector_type(8)));
typedef float  f32x4  __attribute__((ext_vector_type(4)));
typedef float  f32x16 __attribute__((ext_vector_type(16)));
typedef unsigned short u16;

// ---- workspace layout (bytes) ----
#define WCT_OFF   0u          // 144*256 bf16 = 73728   (W^T, fused Wq|Wk|Wv)
#define SC_OFF    73728u      // 144 f32 BN scale
#define SH_OFF    74304u      // 144 f32 BN shift
#define BST_OFF   75008u      // 23 * 16384 bf16-bytes (2-window B frags, frag-lane order)
#define MSUM_OFF  640256u     // 16*16*2 f32 (softmax max, 1/sum)
#define LCB_OFF   642304u     // 16*16*64 f32 (Lc + pos_b)
#define QP_OFF    707840u     // 16*4096*64 bf16 (q, BN'd, [b][pos][ch])
#define KT_OFF    9096448u    // 16*16*4096 bf16 (k, [b][ch][pos])
#define VT_OFF    11193600u   // 16*64*4096 bf16 (v, BN'd, [b][ch][pos] = per-v image)
#define LP_OFF    19582208u   // Lp bf16 [bchunk][pos][v*16+k], 8388608 B per b
#define LP_PER_B  8388608u

// ------------------------------------------------------------------
// Kernel P: precompute WcT (bf16), BN affine, 2-window conv B fragments.
// ------------------------------------------------------------------
__global__ void kP(const float* Wq, const float* Wk, const float* Wv,
                   const float* gq, const float* bq, const float* mq, const float* vq,
                   const float* gv, const float* bv, const float* mv, const float* vvar,
                   const float* pw, char* ws) {
  int t = threadIdx.x;
  if (blockIdx.x == 0) {
    __bf16* wct = (__bf16*)(ws + WCT_OFF);
    for (int i = 0; i < 144; ++i) {
      int n = i, c = t;
      float val;
      if (n < 64)      val = Wq[c * 64 + n];
      else if (n < 80) val = Wk[c * 16 + (n - 64)];
      else             val = Wv[c * 64 + (n - 80)];
      wct[n * 256 + c] = (__bf16)val;
    }
    if (t < 144) {
      float s, sh;
      if (t < 64)      { s = gq[t] * rsqrtf(vq[t] + 1e-3f); sh = bq[t] - mq[t] * s; }
      else if (t < 80) { s = 1.f; sh = 0.f; }
      else { int i = t - 80; s = gv[i] * rsqrtf(vvar[i] + 1e-3f); sh = bv[i] - mv[i] * s; }
      ((float*)(ws + SC_OFF))[t] = s;
      ((float*)(ws + SH_OFF))[t] = sh;
    }
  } else {
    int dy = blockIdx.x - 1;               // 0..22
    __bf16* bst = (__bf16*)(ws + BST_OFF) + dy * 8192;
    for (int i = 0; i < 32; ++i) {
      int idx = i * 256 + t;               // < 8192
      int nt = idx >> 10;
      int w2 = (idx >> 9) & 1;
      int l  = (idx >> 3) & 63;
      int e  = idx & 7;
      int n  = nt * 32 + (l & 31);
      int xr = n >> 4, kch = n & 15;
      int o1 = (2 * nt + 5) & ~7;
      int j  = o1 + w2 * 16 + (l >> 5) * 8 + e;
      int dxw = j - xr - 5;
      float val = (dxw >= 0 && dxw < 23) ? pw[(dy * 23 + dxw) * 16 + kch] : 0.f;
      bst[idx] = (__bf16)val;
    }
  }
}

// ------------------------------------------------------------------
// Kernel A: fused q/k/v projections (M=65536,K=256,N=144) + BN, MFMA 16x16x32
// q-part stored via LDS transpose -> dense bf16x8 global stores.
// ------------------------------------------------------------------
__global__ __launch_bounds__(256) void kA(const float* x, char* ws) {
  __shared__ __align__(16) u16 qlds[256 * 72];   // 256 pos x 64ch (pad 72), 36864B
  int t = threadIdx.x, w = t >> 6, l = t & 63;
  int m0 = blockIdx.x * 256;
  int b = m0 >> 12;
  int posb = m0 & 4095;
  const __bf16* wct = (const __bf16*)(ws + WCT_OFF);
  const float* sc = (const float*)(ws + SC_OFF);
  const float* sh = (const float*)(ws + SH_OFF);
  __bf16* qp = (__bf16*)(ws + QP_OFF);
  __bf16* kt = (__bf16*)(ws + KT_OFF);
  __bf16* vt = (__bf16*)(ws + VT_OFF);

  int rl = l & 15;      // A row / B col / C col within frag
  int kg = l >> 4;      // k-group 0..3

  f32x4 acc[4][9];
#pragma unroll
  for (int mf = 0; mf < 4; ++mf)
#pragma unroll
    for (int nf = 0; nf < 9; ++nf)
#pragma unroll
      for (int q = 0; q < 4; ++q) acc[mf][nf][q] = 0.f;

  for (int ks = 0; ks < 8; ++ks) {
    bf16x8 a[4];
#pragma unroll
    for (int mf = 0; mf < 4; ++mf) {
      int m = m0 + w * 64 + mf * 16 + rl;
      const float* xp = x + m * 256 + ks * 32 + kg * 8;
      f32x4 v0 = *(const f32x4*)xp;
      f32x4 v1 = *(const f32x4*)(xp + 4);
      bf16x8 av;
      av[0] = (__bf16)v0[0]; av[1] = (__bf16)v0[1]; av[2] = (__bf16)v0[2]; av[3] = (__bf16)v0[3];
      av[4] = (__bf16)v1[0]; av[5] = (__bf16)v1[1]; av[6] = (__bf16)v1[2]; av[7] = (__bf16)v1[3];
      a[mf] = av;
    }
#pragma unroll
    for (int nf = 0; nf < 9; ++nf) {
      bf16x8 bfr = *(const bf16x8*)(wct + (nf * 16 + rl) * 256 + ks * 32 + kg * 8);
#pragma unroll
      for (int mf = 0; mf < 4; ++mf)
        acc[mf][nf] = __builtin_amdgcn_mfma_f32_16x16x32_bf16(a[mf], bfr, acc[mf][nf], 0, 0, 0);
    }
  }

#pragma unroll
  for (int nf = 0; nf < 9; ++nf) {
    int ch = nf * 16 + rl;
    float s = sc[ch], shv = sh[ch];
#pragma unroll
    for (int mf = 0; mf < 4; ++mf) {
      int pbase = w * 64 + mf * 16 + kg * 4;   // pos within block
      union { __bf16 h[4]; uint2 u; } pk;
#pragma unroll
      for (int r = 0; r < 4; ++r) pk.h[r] = (__bf16)(acc[mf][nf][r] * s + shv);
      if (ch < 64) {
#pragma unroll
        for (int r = 0; r < 4; ++r)
          qlds[(pbase + r) * 72 + ch] = ((u16*)&pk.h[r])[0];
      } else if (ch < 80) {
        *(uint2*)(kt + (size_t)(b * 16 + ch - 64) * 4096 + posb + pbase) = pk.u;
      } else {
        *(uint2*)(vt + (size_t)(b * 64 + ch - 80) * 4096 + posb + pbase) = pk.u;
      }
    }
  }
  __syncthreads();
  // dense readback: 2048 chunks of 8 bf16
#pragma unroll
  for (int i = 0; i < 8; ++i) {
    int chunk = t + i * 256;
    int row = chunk >> 3, seg = chunk & 7;
    bf16x8 vq_ = *(const bf16x8*)(qlds + row * 72 + seg * 8);
    *(bf16x8*)(qp + (size_t)(b * 4096 + posb + row) * 64 + seg * 8) = vq_;
  }
}

// ------------------------------------------------------------------
// Kernel B1: per (b, k-channel) softmax max & 1/sum over 4096 positions
// ------------------------------------------------------------------
__global__ void kB1(char* ws) {
  __shared__ float red[256];
  int t = threadIdx.x;
  int b = blockIdx.x >> 4, kk = blockIdx.x & 15;
  const __bf16* kt = (const __bf16*)(ws + KT_OFF) + (size_t)(b * 16 + kk) * 4096;
  float v[16];
  bf16x8 c0 = *(const bf16x8*)(kt + t * 16);
  bf16x8 c1 = *(const bf16x8*)(kt + t * 16 + 8);
#pragma unroll
  for (int i = 0; i < 8; ++i) { v[i] = (float)c0[i]; v[8 + i] = (float)c1[i]; }
  float mx = v[0];
#pragma unroll
  for (int i = 1; i < 16; ++i) mx = fmaxf(mx, v[i]);
  red[t] = mx; __syncthreads();
  for (int s = 128; s > 0; s >>= 1) { if (t < s) red[t] = fmaxf(red[t], red[t + s]); __syncthreads(); }
  mx = red[0]; __syncthreads();
  float se = 0.f;
#pragma unroll
  for (int i = 0; i < 16; ++i) se += expf(v[i] - mx);
  red[t] = se; __syncthreads();
  for (int s = 128; s > 0; s >>= 1) { if (t < s) red[t] += red[t + s]; __syncthreads(); }
  if (t == 0) {
    float* ms = (float*)(ws + MSUM_OFF);
    ms[(b * 16 + kk) * 2] = mx;
    ms[(b * 16 + kk) * 2 + 1] = 1.f / red[0];
  }
}

// ------------------------------------------------------------------
// Kernel B2: LcB[b][k][v] = sum_n softmax(k)[n]*v[v][n] + pos_b[k]
// ------------------------------------------------------------------
__global__ __launch_bounds__(256) void kB2(char* ws, const float* pos_b) {
  __shared__ float red[16][256];
  int t = threadIdx.x;
  int b = blockIdx.x >> 6, v = blockIdx.x & 63;
  const __bf16* kt = (const __bf16*)(ws + KT_OFF) + (size_t)b * 16 * 4096;
  const __bf16* vt = (const __bf16*)(ws + VT_OFF) + (size_t)(b * 64 + v) * 4096;
  const float* ms = (const float*)(ws + MSUM_OFF) + b * 32;
  float mx[16];
#pragma unroll
  for (int i = 0; i < 16; ++i) mx[i] = ms[2 * i];
  float acc[16];
#pragma unroll
  for (int i = 0; i < 16; ++i) acc[i] = 0.f;
  for (int c = 0; c < 16; ++c) {
    int p = c * 256 + t;
    float vv = (float)vt[p];
#pragma unroll
    for (int i = 0; i < 16; ++i)
      acc[i] += expf((float)kt[i * 4096 + p] - mx[i]) * vv;
  }
#pragma unroll
  for (int i = 0; i < 16; ++i) red[i][t] = acc[i];
  __syncthreads();
  for (int s = 128; s > 0; s >>= 1) {
    if (t < s) {
#pragma unroll
      for (int i = 0; i < 16; ++i) red[i][t] += red[i][t + s];
    }
    __syncthreads();
  }
  if (t < 16) {
    float* lcb = (float*)(ws + LCB_OFF);
    lcb[(b * 16 + t) * 64 + v] = red[t][0] * ms[2 * t + 1] + pos_b[t];
  }
}

// ------------------------------------------------------------------
// Kernel C: 23x23 conv as banded GEMM, 2 aligned K=16 windows.
// 512-thr block, 8 waves = (v_local 2) x (nt-pair ntp 4). Per wave:
// M=64 rows (one v), N=64 (2 nt sharing window base o1), acc[2][2] = 64 regs
// -> 4 waves/SIMD via __launch_bounds__(512,4). Per dy per wave:
// 4 A-reads + 4 B-reads + 8 MFMA. B triple-buffered, 1 barrier/dy, vmcnt(2).
// ------------------------------------------------------------------
__global__ __launch_bounds__(512, 4) void kC(char* ws, int b0) {
  __shared__ __align__(16) u16 imgp[2 * 86 * 56];   // [vs][rr][56], 19264B
  __shared__ __align__(16) u16 bbuf[3][8192];       // triple-buffered B, 16KB each
  int t = threadIdx.x, w = t >> 6, l = t & 63;
  int bb = blockIdx.x >> 7;
  int b = b0 + bb;
  int rest = blockIdx.x & 127;
  int vg = rest >> 2, xt = rest & 3;
  int vbase = vg * 2, x0g = xt * 16;
  const __bf16* vt = (const __bf16*)(ws + VT_OFF);
  const char* bstc = (const char*)(ws + BST_OFF);
  __bf16* lp = (__bf16*)(ws + LP_OFF) + (size_t)bb * 4194304;

  int v_local = w & 1, ntp = w >> 1;
  int hh = l >> 5;            // k-half
  int rr0 = l & 31;           // row within 32-row m-frag
  int o1 = (4 * ntp + 5) & ~7;   // shared window base for nt pair {2ntp, 2ntp+1}

  // zero the image buffer (1204 x 16B)
  bf16x8 z;
#pragma unroll
  for (int q = 0; q < 8; ++q) z[q] = (__bf16)0.f;
#pragma unroll
  for (int i = 0; i < 3; ++i) {
    int idx = t + i * 512;
    if (idx < 1204) ((bf16x8*)imgp)[idx] = z;
  }
  __syncthreads();
  // stage interior: rows 11..74 hold image rows y=0..63, cols [0,48) used
#pragma unroll
  for (int i = 0; i < 2; ++i) {
    int slot = t + i * 512;            // < 768 = 2v * 64y * 6 chunks
    if (slot < 768) {
      int vs = slot / 384, rem = slot % 384;
      int y = rem / 6, c0 = (rem % 6) * 8;
      int gx = x0g - 16 + c0;
      if (gx >= 0 && gx < 64) {
        bf16x8 val = *(const bf16x8*)(vt + (size_t)(b * 64 + vbase + vs) * 4096 + y * 64 + gx);
        *(bf16x8*)(imgp + vs * 4816 + (11 + y) * 56 + c0) = val;
      }
    }
  }

  // per-lane B fragment offsets (u16) within one bbuf: [nt][w2][lane][8]
  int boff[2][2];
#pragma unroll
  for (int j = 0; j < 2; ++j)
#pragma unroll
    for (int w2 = 0; w2 < 2; ++w2)
      boff[j][w2] = ((((2 * ntp + j) * 2 + w2) * 64) + l) * 8;

  // per-mf A base (u16 index into imgp), advanced by 56 per dy
  int abase[2];
#pragma unroll
  for (int mf = 0; mf < 2; ++mf)
    abase[mf] = v_local * 4816 + (mf * 32 + rr0) * 56 + o1 + hh * 8;

  f32x16 acc[2][2];
#pragma unroll
  for (int mf = 0; mf < 2; ++mf)
#pragma unroll
    for (int j = 0; j < 2; ++j)
#pragma unroll
      for (int q = 0; q < 16; ++q) acc[mf][j][q] = 0.f;

  // async stage: 2 x 16B per thread, linear frag-order.
  // LDS dest = wave-uniform base (HW adds lane*16); global src has + l*16.
#define STAGE_B(bufsel, dyv) do {                                              \
    const char* gsrc = bstc + (dyv) * 16384 + w * 1024 + l * 16;               \
    char* ldsb = (char*)&bbuf[0][0] + (bufsel) * 16384 + w * 1024;             \
    _Pragma("unroll")                                                          \
    for (int i_ = 0; i_ < 2; ++i_)                                             \
      __builtin_amdgcn_global_load_lds(                                        \
        (const __attribute__((address_space(1))) void*)(gsrc + i_ * 8192),     \
        (__attribute__((address_space(3))) void*)(ldsb + i_ * 8192), 16, 0, 0);\
  } while (0)

  STAGE_B(0, 0);
  __syncthreads();   // imgp staging complete

  int cur = 0;
  for (int dy = 0; dy < 23; ++dy) {
    int nxt = cur + 1; if (nxt == 3) nxt = 0;
    if (dy < 22) {
      STAGE_B(nxt, dy + 1);
      asm volatile("s_waitcnt vmcnt(2)" ::: "memory");
    } else {
      asm volatile("s_waitcnt vmcnt(0)" ::: "memory");
    }
    __builtin_amdgcn_s_barrier();
    asm volatile("" ::: "memory");

    const u16* bq = &bbuf[0][0] + cur * 8192;
    // A fragments: 2 windows (o1, o1+16) per mf
    bf16x8 a[2][2];
#pragma unroll
    for (int mf = 0; mf < 2; ++mf) {
      const u16* base = imgp + abase[mf] + dy * 56;
      a[mf][0] = *(const bf16x8*)(base);
      a[mf][1] = *(const bf16x8*)(base + 16);
    }
#pragma unroll
    for (int w2 = 0; w2 < 2; ++w2) {
#pragma unroll
      for (int j = 0; j < 2; ++j) {
        bf16x8 bfr = *(const bf16x8*)(bq + boff[j][w2]);
        acc[0][j] = __builtin_amdgcn_mfma_f32_32x32x16_bf16(a[0][w2], bfr, acc[0][j], 0, 0, 0);
        acc[1][j] = __builtin_amdgcn_mfma_f32_32x32x16_bf16(a[1][w2], bfr, acc[1][j], 0, 0, 0);
      }
    }
    cur = nxt;
  }
#undef STAGE_B

  // epilogue: Lp[pos][v*16+k] bf16
  int v = vbase + v_local;
#pragma unroll
  for (int mf = 0; mf < 2; ++mf) {
#pragma unroll
    for (int j = 0; j < 2; ++j) {
      int n = (2 * ntp + j) * 32 + (l & 31);
      int x = x0g + (n >> 4), kch = n & 15;
#pragma unroll
      for (int r = 0; r < 16; ++r) {
        int y = mf * 32 + (r & 3) + 8 * (r >> 2) + 4 * (l >> 5);
        lp[(size_t)(y * 64 + x) * 1024 + v * 16 + kch] = (__bf16)acc[mf][j][r];
      }
    }
  }
}

// ------------------------------------------------------------------
// Kernel D: Y[b][pos][h*64+v] = sum_k q[pos][h*16+k]*(LcB[k][v] + Lp[pos][v*16+k])
// ------------------------------------------------------------------
__global__ __launch_bounds__(256) void kD(const char* ws, float* out, int b0) {
  int t = threadIdx.x;
  int h = t >> 6, v = t & 63;
  int bb = blockIdx.x >> 6, pt = blockIdx.x & 63;
  int b = b0 + bb;
  const __bf16* qp = (const __bf16*)(ws + QP_OFF) + (size_t)b * 4096 * 64;
  const __bf16* lp = (const __bf16*)(ws + LP_OFF) + (size_t)bb * 4194304;
  const float* lcb = (const float*)(ws + LCB_OFF) + b * 1024;
  float lc[16];
#pragma unroll
  for (int i = 0; i < 16; ++i) lc[i] = lcb[i * 64 + v];
  int p0 = pt * 64;
  for (int pp = 0; pp < 64; ++pp) {
    int p = p0 + pp;
    const __bf16* qrow = qp + (size_t)p * 64 + h * 16;
    const __bf16* lrow = lp + (size_t)p * 1024 + v * 16;
    bf16x8 q0 = *(const bf16x8*)qrow;
    bf16x8 q1 = *(const bf16x8*)(qrow + 8);
    bf16x8 l0 = *(const bf16x8*)lrow;
    bf16x8 l1 = *(const bf16x8*)(lrow + 8);
    float sum = 0.f;
#pragma unroll
    for (int i = 0; i < 8; ++i) {
      sum += (float)q0[i] * (lc[i] + (float)l0[i]);
      sum += (float)q1[i] * (lc[8 + i] + (float)l1[i]);
    }
    out[((size_t)b * 4096 + p) * 256 + t] = sum;
  }
}

extern "C" void kernel_launch(void* const* d_in, const int* in_sizes, int n_in,
                              void* d_out, int out_size, void* d_ws, size_t ws_size,
                              hipStream_t stream) {
  const float* x   = (const float*)d_in[0];
  const float* Wq  = (const float*)d_in[1];
  const float* Wk  = (const float*)d_in[2];
  const float* Wv  = (const float*)d_in[3];
  const float* gq  = (const float*)d_in[4];
  const float* bq  = (const float*)d_in[5];
  const float* mq  = (const float*)d_in[6];
  const float* vq  = (const float*)d_in[7];
  const float* gv  = (const float*)d_in[8];
  const float* bv  = (const float*)d_in[9];
  const float* mv  = (const float*)d_in[10];
  const float* vvr = (const float*)d_in[11];
  const float* pw  = (const float*)d_in[12];
  const float* pb  = (const float*)d_in[13];
  char* ws = (char*)d_ws;
  float* out = (float*)d_out;

  hipLaunchKernelGGL(kP, dim3(24), dim3(256), 0, stream,
                     Wq, Wk, Wv, gq, bq, mq, vq, gv, bv, mv, vvr, pw, ws);
  hipLaunchKernelGGL(kA, dim3(256), dim3(256), 0, stream, x, ws);
  hipLaunchKernelGGL(kB1, dim3(256), dim3(256), 0, stream, ws);
  hipLaunchKernelGGL(kB2, dim3(1024), dim3(256), 0, stream, ws, pb);

  size_t avail = ws_size > LP_OFF ? ws_size - LP_OFF : 0;
  int nb = (int)(avail / LP_PER_B);
  if (nb < 1) nb = 1;
  if (nb > 16) nb = 16;
  for (int b0 = 0; b0 < 16; b0 += nb) {
    int cur = (16 - b0 < nb) ? 16 - b0 : nb;
    hipLaunchKernelGGL(kC, dim3(cur * 128), dim3(512), 0, stream, ws, b0);
    hipLaunchKernelGGL(kD, dim3(cur * 64), dim3(256), 0, stream, ws, out, b0);
  }
}

// Round 9
// 214.197 us; speedup vs baseline: 6.0444x; 1.0932x over previous
//
#include <hip/hip_runtime.h>
#include <stdint.h>

typedef __bf16 bf16x8 __attribute__((ext_vector_type(8)));
typedef float  f32x4  __attribute__((ext_vector_type(4)));
typedef float  f32x16 __attribute__((ext_vector_type(16)));
typedef unsigned short u16;

// ---- workspace layout (bytes) ----
#define WCT_OFF   0u          // 144*256 bf16 = 73728   (W^T, fused Wq|Wk|Wv)
#define SC_OFF    73728u      // 144 f32 BN scale
#define SH_OFF    74304u      // 144 f32 BN shift
#define BST_OFF   75008u      // 23 * 16384 B (2-window conv B frags, frag-lane order)
#define ZB_OFF    524288u     // 4096 B of zeros (OOB guard for img staging)
#define MSUM_OFF  640256u     // 16*16*2 f32 (softmax max, 1/sum)
#define LCB_OFF   642304u     // 16*16*64 f32 (Lc + pos_b)
#define QP_OFF    707840u     // 16*4096*64 bf16 (q, BN'd, [b][pos][ch])
#define KT_OFF    9096448u    // 16*16*4096 bf16 (k, [b][ch][pos])
#define VT_OFF    11193600u   // 16*64*4096 bf16 (v, BN'd, [b][ch][pos] = per-v image)

// ------------------------------------------------------------------
// Kernel P: WcT (bf16), BN affine, 2-window conv B fragments, zero guard.
// ------------------------------------------------------------------
__global__ void kP(const float* Wq, const float* Wk, const float* Wv,
                   const float* gq, const float* bq, const float* mq, const float* vq,
                   const float* gv, const float* bv, const float* mv, const float* vvar,
                   const float* pw, char* ws) {
  int t = threadIdx.x;
  if (blockIdx.x == 0) {
    __bf16* wct = (__bf16*)(ws + WCT_OFF);
    for (int i = 0; i < 144; ++i) {
      int n = i, c = t;
      float val;
      if (n < 64)      val = Wq[c * 64 + n];
      else if (n < 80) val = Wk[c * 16 + (n - 64)];
      else             val = Wv[c * 64 + (n - 80)];
      wct[n * 256 + c] = (__bf16)val;
    }
    if (t < 144) {
      float s, sh;
      if (t < 64)      { s = gq[t] * rsqrtf(vq[t] + 1e-3f); sh = bq[t] - mq[t] * s; }
      else if (t < 80) { s = 1.f; sh = 0.f; }
      else { int i = t - 80; s = gv[i] * rsqrtf(vvar[i] + 1e-3f); sh = bv[i] - mv[i] * s; }
      ((float*)(ws + SC_OFF))[t] = s;
      ((float*)(ws + SH_OFF))[t] = sh;
    }
    f32x4 fz;
    fz[0] = 0.f; fz[1] = 0.f; fz[2] = 0.f; fz[3] = 0.f;
    *(f32x4*)(ws + ZB_OFF + t * 16) = fz;     // 256*16 = 4096 B of zeros
  } else {
    int dy = blockIdx.x - 1;               // 0..22
    __bf16* bst = (__bf16*)(ws + BST_OFF) + dy * 8192;
    for (int i = 0; i < 32; ++i) {
      int idx = i * 256 + t;               // < 8192
      int nt = idx >> 10;
      int w2 = (idx >> 9) & 1;
      int l  = (idx >> 3) & 63;
      int e  = idx & 7;
      int n  = nt * 32 + (l & 31);
      int xr = n >> 4, kch = n & 15;
      int o1 = (2 * nt + 5) & ~7;
      int j  = o1 + w2 * 16 + (l >> 5) * 8 + e;
      int dxw = j - xr - 5;
      float val = (dxw >= 0 && dxw < 23) ? pw[(dy * 23 + dxw) * 16 + kch] : 0.f;
      bst[idx] = (__bf16)val;
    }
  }
}

// ------------------------------------------------------------------
// Kernel A: fused q/k/v projections + BN, MFMA 16x16x32.
// Grid 1024, M=64/block (4 blocks/CU).
// ------------------------------------------------------------------
__global__ __launch_bounds__(256) void kA(const float* x, char* ws) {
  __shared__ __align__(16) u16 qlds[64 * 72];   // 64 pos x 64ch (pad 72), 9216B
  int t = threadIdx.x, w = t >> 6, l = t & 63;
  int m0 = blockIdx.x * 64;
  int b = m0 >> 12;
  int posb = m0 & 4095;
  const __bf16* wct = (const __bf16*)(ws + WCT_OFF);
  const float* sc = (const float*)(ws + SC_OFF);
  const float* sh = (const float*)(ws + SH_OFF);
  __bf16* qp = (__bf16*)(ws + QP_OFF);
  __bf16* kt = (__bf16*)(ws + KT_OFF);
  __bf16* vt = (__bf16*)(ws + VT_OFF);

  int rl = l & 15;
  int kg = l >> 4;

  f32x4 acc[9];
#pragma unroll
  for (int nf = 0; nf < 9; ++nf)
#pragma unroll
    for (int q = 0; q < 4; ++q) acc[nf][q] = 0.f;

  for (int ks = 0; ks < 8; ++ks) {
    int m = m0 + w * 16 + rl;
    const float* xp = x + (size_t)m * 256 + ks * 32 + kg * 8;
    f32x4 v0 = *(const f32x4*)xp;
    f32x4 v1 = *(const f32x4*)(xp + 4);
    bf16x8 a;
    a[0] = (__bf16)v0[0]; a[1] = (__bf16)v0[1]; a[2] = (__bf16)v0[2]; a[3] = (__bf16)v0[3];
    a[4] = (__bf16)v1[0]; a[5] = (__bf16)v1[1]; a[6] = (__bf16)v1[2]; a[7] = (__bf16)v1[3];
#pragma unroll
    for (int nf = 0; nf < 9; ++nf) {
      bf16x8 bfr = *(const bf16x8*)(wct + (nf * 16 + rl) * 256 + ks * 32 + kg * 8);
      acc[nf] = __builtin_amdgcn_mfma_f32_16x16x32_bf16(a, bfr, acc[nf], 0, 0, 0);
    }
  }

#pragma unroll
  for (int nf = 0; nf < 9; ++nf) {
    int ch = nf * 16 + rl;
    float s = sc[ch], shv = sh[ch];
    int pbase = w * 16 + kg * 4;
    union { __bf16 h[4]; uint2 u; } pk;
#pragma unroll
    for (int r = 0; r < 4; ++r) pk.h[r] = (__bf16)(acc[nf][r] * s + shv);
    if (ch < 64) {
#pragma unroll
      for (int r = 0; r < 4; ++r)
        qlds[(pbase + r) * 72 + ch] = ((u16*)&pk.h[r])[0];
    } else if (ch < 80) {
      *(uint2*)(kt + (size_t)(b * 16 + ch - 64) * 4096 + posb + pbase) = pk.u;
    } else {
      *(uint2*)(vt + (size_t)(b * 64 + ch - 80) * 4096 + posb + pbase) = pk.u;
    }
  }
  __syncthreads();
  // dense readback: 512 chunks of 8 bf16
#pragma unroll
  for (int i = 0; i < 2; ++i) {
    int chunk = t + i * 256;
    int row = chunk >> 3, seg = chunk & 7;
    bf16x8 vq_ = *(const bf16x8*)(qlds + row * 72 + seg * 8);
    *(bf16x8*)(qp + (size_t)(b * 4096 + posb + row) * 64 + seg * 8) = vq_;
  }
}

// ------------------------------------------------------------------
// Kernel B1: per (b, k-channel) softmax max & 1/sum over 4096 positions
// ------------------------------------------------------------------
__global__ void kB1(char* ws) {
  __shared__ float red[256];
  int t = threadIdx.x;
  int b = blockIdx.x >> 4, kk = blockIdx.x & 15;
  const __bf16* kt = (const __bf16*)(ws + KT_OFF) + (size_t)(b * 16 + kk) * 4096;
  float v[16];
  bf16x8 c0 = *(const bf16x8*)(kt + t * 16);
  bf16x8 c1 = *(const bf16x8*)(kt + t * 16 + 8);
#pragma unroll
  for (int i = 0; i < 8; ++i) { v[i] = (float)c0[i]; v[8 + i] = (float)c1[i]; }
  float mx = v[0];
#pragma unroll
  for (int i = 1; i < 16; ++i) mx = fmaxf(mx, v[i]);
  red[t] = mx; __syncthreads();
  for (int s = 128; s > 0; s >>= 1) { if (t < s) red[t] = fmaxf(red[t], red[t + s]); __syncthreads(); }
  mx = red[0]; __syncthreads();
  float se = 0.f;
#pragma unroll
  for (int i = 0; i < 16; ++i) se += expf(v[i] - mx);
  red[t] = se; __syncthreads();
  for (int s = 128; s > 0; s >>= 1) { if (t < s) red[t] += red[t + s]; __syncthreads(); }
  if (t == 0) {
    float* ms = (float*)(ws + MSUM_OFF);
    ms[(b * 16 + kk) * 2] = mx;
    ms[(b * 16 + kk) * 2 + 1] = 1.f / red[0];
  }
}

// ------------------------------------------------------------------
// Kernel B2: LcB[b][k][v] = sum_n softmax(k)[n]*v[v][n] + pos_b[k]
// ------------------------------------------------------------------
__global__ __launch_bounds__(256) void kB2(char* ws, const float* pos_b) {
  __shared__ float red[16][256];
  int t = threadIdx.x;
  int b = blockIdx.x >> 6, v = blockIdx.x & 63;
  const __bf16* kt = (const __bf16*)(ws + KT_OFF) + (size_t)b * 16 * 4096;
  const __bf16* vt = (const __bf16*)(ws + VT_OFF) + (size_t)(b * 64 + v) * 4096;
  const float* ms = (const float*)(ws + MSUM_OFF) + b * 32;
  float mx[16];
#pragma unroll
  for (int i = 0; i < 16; ++i) mx[i] = ms[2 * i];
  float acc[16];
#pragma unroll
  for (int i = 0; i < 16; ++i) acc[i] = 0.f;
  for (int c = 0; c < 16; ++c) {
    int p = c * 256 + t;
    float vv = (float)vt[p];
#pragma unroll
    for (int i = 0; i < 16; ++i)
      acc[i] += expf((float)kt[i * 4096 + p] - mx[i]) * vv;
  }
#pragma unroll
  for (int i = 0; i < 16; ++i) red[i][t] = acc[i];
  __syncthreads();
  for (int s = 128; s > 0; s >>= 1) {
    if (t < s) {
#pragma unroll
      for (int i = 0; i < 16; ++i) red[i][t] += red[i][t + s];
    }
    __syncthreads();
  }
  if (t < 16) {
    float* lcb = (float*)(ws + LCB_OFF);
    lcb[(b * 16 + t) * 64 + v] = red[t][0] * ms[2 * t + 1] + pos_b[t];
  }
}

// ------------------------------------------------------------------
// Kernel C (FUSED conv + combine), race-free rewrite:
// NO ds_write in the loop. Image ring (3 slots) staged via global_load_lds
// with PRE-SWIZZLED per-lane global source (linear LDS dest, m173 pattern);
// OOB/halo lanes read a zero guard page. All in-loop LDS writes are DMA ops
// counted by per-wave vmcnt -> the proven R3-R6 sync pattern:
//   top of dy: s_waitcnt vmcnt(2); s_barrier   (vmcnt(0) at dy=22)
//   body  dy : issue SI(slot (dy+2)%3, row y0+dy-9); issue SB(buf (dy+2)%3);
//              ds_read af/bi; 8 MFMA
// Issue-after-barrier guarantees the written slot's last readers (iter dy-1)
// are done; FIFO vmcnt(2) guarantees this iter's inputs have landed while the
// next B-table pair stays in flight.
// ------------------------------------------------------------------
__global__ __launch_bounds__(512, 4) void kC(char* ws, float* out) {
  __shared__ __align__(16) u16 img[3][64][64];    // 24576 B  [slot][v][col]
  __shared__ __align__(16) u16 bbuf[3][8192];     // 49152 B
  __shared__ __align__(16) u16 qt[2048];          // 4096 B   [yy][x16][ch64]
  int t = threadIdx.x, w = t >> 6, l = t & 63;
  int b = blockIdx.x >> 7;
  int rest = blockIdx.x & 127;
  int yp = rest >> 2, xt = rest & 3;
  int y0 = yp * 2, x0g = xt * 16;
  const __bf16* vt  = (const __bf16*)(ws + VT_OFF);
  const __bf16* qp  = (const __bf16*)(ws + QP_OFF);
  const float*  lcb = (const float*)(ws + LCB_OFF) + b * 1024;
  const char*   bstc = (const char*)(ws + BST_OFF);
  const char*   zb   = (const char*)(ws + ZB_OFF) + (t & 255) * 16;

  int yy = w >> 2, ntp = w & 3;
  int hh = l >> 5;
  int o1_8 = ((4 * ntp + 5) & ~7) >> 3;    // shared window base / 8 for the nt-pair

  // img staging lane map: LDS linear [sv][sc8*8]; global chunk = sc8 ^ (sv&7)
  int sv = t >> 3, sc8 = t & 7;
  int sgx = x0g - 16 + (sc8 ^ (sv & 7)) * 8;
  bool sokx = (sgx >= 0 && sgx < 64);
  const char* vsrc = (const char*)(vt + (size_t)(b * 64 + sv) * 4096 + sgx);

#define STAGE_IMG(slot, rowv) do {                                             \
    int _r = (rowv);                                                           \
    const char* _s = (sokx && _r >= 0 && _r < 64) ? (vsrc + _r * 128) : zb;    \
    __builtin_amdgcn_global_load_lds(                                          \
      (const __attribute__((address_space(1))) void*)_s,                       \
      (__attribute__((address_space(3))) void*)((char*)&img[0][0][0] + (slot) * 8192 + w * 1024), \
      16, 0, 0);                                                               \
  } while (0)

#define STAGE_B(bufsel, dyv) do {                                              \
    const char* gsrc = bstc + (dyv) * 16384 + w * 1024 + l * 16;               \
    char* ldsb = (char*)&bbuf[0][0] + (bufsel) * 16384 + w * 1024;             \
    _Pragma("unroll")                                                          \
    for (int i_ = 0; i_ < 2; ++i_)                                             \
      __builtin_amdgcn_global_load_lds(                                        \
        (const __attribute__((address_space(1))) void*)(gsrc + i_ * 8192),     \
        (__attribute__((address_space(3))) void*)(ldsb + i_ * 8192), 16, 0, 0);\
  } while (0)

  // ---- prologue: img slots 0,1; B bufs 0,1; q tile (only ds_write, drained) ----
  STAGE_IMG(0, y0 - 11);
  STAGE_IMG(1, y0 - 10);
  STAGE_B(0, 0);
  STAGE_B(1, 1);
  {
    int f0 = t * 4;
    int qyy = f0 >> 10, qx = (f0 >> 6) & 15, qch = f0 & 63;
    *(uint2*)&qt[f0] =
      *(const uint2*)(qp + (size_t)(b * 4096 + (y0 + qyy) * 64 + x0g + qx) * 64 + qch);
  }
  asm volatile("s_waitcnt lgkmcnt(0)" ::: "memory");

  // B fragment offsets (u16) within a bbuf
  int boff[2][2];
#pragma unroll
  for (int j = 0; j < 2; ++j)
#pragma unroll
    for (int w2 = 0; w2 < 2; ++w2)
      boff[j][w2] = ((((2 * ntp + j) * 2 + w2) * 64) + l) * 8;

  f32x16 acc[2][2];
#pragma unroll
  for (int mf = 0; mf < 2; ++mf)
#pragma unroll
    for (int j = 0; j < 2; ++j)
#pragma unroll
      for (int q = 0; q < 16; ++q) acc[mf][j][q] = 0.f;

  int cur = 0;
  for (int dy = 0; dy < 23; ++dy) {
    int nxt = cur + 1; if (nxt == 3) nxt = 0;
    int wsl = nxt + 1; if (wsl == 3) wsl = 0;      // (dy+2)%3
    if (dy < 22) {
      asm volatile("s_waitcnt vmcnt(2)" ::: "memory");
    } else {
      asm volatile("s_waitcnt vmcnt(0)" ::: "memory");
    }
    __builtin_amdgcn_s_barrier();
    __builtin_amdgcn_sched_barrier(0);
    asm volatile("" ::: "memory");

    // issue next-stage DMAs (targets not read in this barrier interval)
    if (dy < 22) STAGE_IMG(wsl, y0 + dy - 9);
    if (dy < 21) STAGE_B(wsl, dy + 2);

    const u16* bq = &bbuf[0][0] + cur * 8192;
    int rsl = yy ? nxt : cur;                      // slot holding row y0+yy+dy-11
    bf16x8 af[2][2], bi[2][2];
#pragma unroll
    for (int j = 0; j < 2; ++j)
#pragma unroll
      for (int w2 = 0; w2 < 2; ++w2)
        af[j][w2] = *(const bf16x8*)(bq + boff[j][w2]);
#pragma unroll
    for (int mf = 0; mf < 2; ++mf) {
      int v = mf * 32 + (l & 31);
#pragma unroll
      for (int w2 = 0; w2 < 2; ++w2)
        bi[mf][w2] = *(const bf16x8*)(&img[rsl][v][((o1_8 + w2 * 2 + hh) ^ (v & 7)) * 8]);
    }
#pragma unroll
    for (int w2 = 0; w2 < 2; ++w2)
#pragma unroll
      for (int j = 0; j < 2; ++j) {
        acc[0][j] = __builtin_amdgcn_mfma_f32_32x32x16_bf16(af[j][w2], bi[0][w2], acc[0][j], 0, 0, 0);
        acc[1][j] = __builtin_amdgcn_mfma_f32_32x32x16_bf16(af[j][w2], bi[1][w2], acc[1][j], 0, 0, 0);
      }
    cur = nxt;
  }
#undef STAGE_IMG
#undef STAGE_B

  // ---- fused epilogue: Y = sum_k q*(Lc + Lp), k lives in acc reg index ----
  float lc[2][16];
#pragma unroll
  for (int mf = 0; mf < 2; ++mf)
#pragma unroll
    for (int r = 0; r < 16; ++r) {
      int k = (r & 3) + 8 * ((r >> 2) & 1) + 4 * hh;
      lc[mf][r] = lcb[k * 64 + mf * 32 + (l & 31)];
    }
  size_t obase = ((size_t)b * 4096 + (y0 + yy) * 64 + x0g) * 256;
#pragma unroll
  for (int j = 0; j < 2; ++j) {
#pragma unroll
    for (int xh = 0; xh < 2; ++xh) {
      int x_local = 2 * (2 * ntp + j) + xh;
      const u16* qrow = &qt[(yy * 16 + x_local) * 64];
#pragma unroll
      for (int h = 0; h < 4; ++h) {
        float s0 = 0.f, s1 = 0.f;
#pragma unroll
        for (int r8 = 0; r8 < 8; ++r8) {
          int r = xh * 8 + r8;
          int k = (r8 & 3) + 8 * (r8 >> 2) + 4 * hh;
          float qv = (float)(*(const __bf16*)&qrow[h * 16 + k]);   // LDS broadcast
          s0 += qv * (acc[0][j][r] + lc[0][r]);
          s1 += qv * (acc[1][j][r] + lc[1][r]);
        }
        s0 += __shfl_xor(s0, 32);
        s1 += __shfl_xor(s1, 32);
        float val = (l >= 32) ? s1 : s0;           // ch = h*64 + l, v = l
        out[obase + (size_t)x_local * 256 + h * 64 + l] = val;
      }
    }
  }
}

extern "C" void kernel_launch(void* const* d_in, const int* in_sizes, int n_in,
                              void* d_out, int out_size, void* d_ws, size_t ws_size,
                              hipStream_t stream) {
  const float* x   = (const float*)d_in[0];
  const float* Wq  = (const float*)d_in[1];
  const float* Wk  = (const float*)d_in[2];
  const float* Wv  = (const float*)d_in[3];
  const float* gq  = (const float*)d_in[4];
  const float* bq  = (const float*)d_in[5];
  const float* mq  = (const float*)d_in[6];
  const float* vq  = (const float*)d_in[7];
  const float* gv  = (const float*)d_in[8];
  const float* bv  = (const float*)d_in[9];
  const float* mv  = (const float*)d_in[10];
  const float* vvr = (const float*)d_in[11];
  const float* pw  = (const float*)d_in[12];
  const float* pb  = (const float*)d_in[13];
  char* ws = (char*)d_ws;
  float* out = (float*)d_out;

  hipLaunchKernelGGL(kP, dim3(24), dim3(256), 0, stream,
                     Wq, Wk, Wv, gq, bq, mq, vq, gv, bv, mv, vvr, pw, ws);
  hipLaunchKernelGGL(kA, dim3(1024), dim3(256), 0, stream, x, ws);
  hipLaunchKernelGGL(kB1, dim3(256), dim3(256), 0, stream, ws);
  hipLaunchKernelGGL(kB2, dim3(1024), dim3(256), 0, stream, ws, pb);
  hipLaunchKernelGGL(kC, dim3(2048), dim3(512), 0, stream, ws, out);
}